// Round 1
// baseline (701.685 us; speedup 1.0000x reference)
//
#include <hip/hip_runtime.h>
#include <math.h>

#define BATCH 4096
#define DIM 128
#define LU 10
#define LI 20

__device__ __forceinline__ float wave_reduce64(float v) {
    for (int m = 32; m >= 1; m >>= 1) v += __shfl_xor(v, m, 64);
    return v;
}

// ---------------------------------------------------------------------------
// K1: branch attention + pooled@W + triplet losses. 8 samples per block.
// ---------------------------------------------------------------------------
__global__ __launch_bounds__(256) void k1_branches(
    const int* __restrict__ user_idx, const int* __restrict__ user_feat,
    const int* __restrict__ pos_idx, const int* __restrict__ pos_feat,
    const int* __restrict__ neg_idx, const int* __restrict__ neg_feat,
    const float* __restrict__ emb_user, const float* __restrict__ emb_item,
    const float* __restrict__ ef_user, const float* __restrict__ ef_item,
    const float* __restrict__ pop_u, const float* __restrict__ int_u,
    const float* __restrict__ pop_i, const float* __restrict__ int_i,
    const float* __restrict__ W_pop, const float* __restrict__ b_pop,
    const float* __restrict__ W_int, const float* __restrict__ b_int,
    float* __restrict__ out_hot, float* __restrict__ out_cold)
{
    __shared__ float fuse[LI + 1][DIM];
    __shared__ float pooled[8][2][DIM];
    __shared__ float sc[2][LI + 1];
    __shared__ float wgt[2][LI + 1];
    __shared__ int   smask[LI + 1];
    __shared__ float red[4][8];

    const int t    = threadIdx.x;
    const int s0   = blockIdx.x * 8;
    const int col  = t & 127;
    const int half = t >> 7;   // 0: hot/W_pop, 1: cold/W_int
    const int wv   = t >> 6;   // wave id 0..3 (0,1 -> hot scores; 2,3 -> cold)
    const int lid  = t & 63;

    float ures[8], pres[8], nres[8];

    for (int b = 0; b < 3; ++b) {
        for (int s = 0; s < 8; ++s) {
            const int i = s0 + s;
            int L, idx;
            const int* feats;
            const float* etab;
            const float* ftab;
            if (b == 0)      { L = LU; idx = user_idx[i]; feats = user_feat + i * LU; etab = emb_user; ftab = ef_user; }
            else if (b == 1) { L = LI; idx = pos_idx[i];  feats = pos_feat + i * LI;  etab = emb_item; ftab = ef_item; }
            else             { L = LI; idx = neg_idx[i];  feats = neg_feat + i * LI;  etab = emb_item; ftab = ef_item; }

            // load fuse rows (even rows by half 0, odd rows by half 1)
            for (int r = half; r <= L; r += 2) {
                float v; int m;
                if (r == 0) { v = etab[(size_t)idx * DIM + col]; m = 1; }
                else        { int f = feats[r - 1]; m = f; v = ftab[(size_t)f * DIM + col]; }
                fuse[r][col] = v;
                if (col == 0) smask[r] = m;
            }
            __syncthreads();

            // scores: waves 0,1 -> pop vec; waves 2,3 -> int vec
            const float* vec = (b == 0) ? ((wv < 2) ? pop_u : int_u)
                                        : ((wv < 2) ? pop_i : int_i);
            float v0 = vec[lid], v1 = vec[lid + 64];
            for (int l = (wv & 1); l <= L; l += 2) {
                float p = fuse[l][lid] * v0 + fuse[l][lid + 64] * v1;
                p = wave_reduce64(p);
                if (lid == 0) sc[wv >> 1][l] = p;
            }
            __syncthreads();

            // softmax (thread 0: hot, thread 1: cold)
            if (t < 2) {
                float m = -1e30f;
                for (int l = 0; l <= L; ++l)
                    if (smask[l] != 0) m = fmaxf(m, sc[t][l]);
                float ssum = 0.f;
                for (int l = 0; l <= L; ++l) {
                    float e = (smask[l] != 0) ? expf(sc[t][l] - m) : 0.f;
                    wgt[t][l] = e;
                    ssum += e;
                }
                float r = 1.f / ssum;
                for (int l = 0; l <= L; ++l) wgt[t][l] *= r;
            }
            __syncthreads();

            // pooled vector (threads 0..127: hot, 128..255: cold)
            float acc = 0.f;
            for (int l = 0; l <= L; ++l) acc += wgt[half][l] * fuse[l][col];
            pooled[s][half][col] = acc;
            __syncthreads();
        }

        // matmul: pooled @ (W_pop | W_int) + bias, 8 samples at once
        const float* W    = half ? W_int : W_pop;
        const float* bias = half ? b_int : b_pop;
        float acc[8];
        {
            float bj = bias[col];
            for (int s = 0; s < 8; ++s) acc[s] = bj;
        }
        for (int d = 0; d < DIM; ++d) {
            float w = W[d * DIM + col];
            for (int s = 0; s < 8; ++s) acc[s] += pooled[s][half][d] * w;
        }
        if (b == 0)      for (int s = 0; s < 8; ++s) ures[s] = acc[s];
        else if (b == 1) for (int s = 0; s < 8; ++s) pres[s] = acc[s];
        else             for (int s = 0; s < 8; ++s) nres[s] = acc[s];
        __syncthreads();
    }

    // triplet losses
    float part[8];
    for (int s = 0; s < 8; ++s) {
        float dp = ures[s] - pres[s];
        float dn = ures[s] - nres[s];
        part[s] = dp * dp - dn * dn;
    }
    for (int s = 0; s < 8; ++s) part[s] = wave_reduce64(part[s]);
    if (lid == 0)
        for (int s = 0; s < 8; ++s) red[wv][s] = part[s];
    __syncthreads();
    if (t < 8) {
        float v = red[0][t] + red[1][t] + 1.0f;
        out_hot[s0 + t] = v > 0.f ? v : 0.f;
    } else if (t < 16) {
        int s = t - 8;
        float v = red[2][s] + red[3][s] + 1.0f;
        out_cold[s0 + s] = v > 0.f ? v : 0.f;
    }
}

// ---------------------------------------------------------------------------
// K2: encoder GEMM (gathered x) + mu/logvar + z + kld/mmi/zsq partials.
// 16 samples per block.
// ---------------------------------------------------------------------------
__global__ __launch_bounds__(256) void k2_encoder(
    const int* __restrict__ pos_feat, const int* __restrict__ pos_idx,
    const int* __restrict__ comp_idx,
    const float* __restrict__ ef_item, const float* __restrict__ emb_item,
    const float* __restrict__ eps,
    const float* __restrict__ enc_W, const float* __restrict__ enc_b,
    const float* __restrict__ fc11_W, const float* __restrict__ fc11_b,
    const float* __restrict__ fc12_W, const float* __restrict__ fc12_b,
    float* __restrict__ zbuf, float* __restrict__ k2part)
{
    __shared__ int   featsL[16 * LI];
    __shared__ float xs[16][32];
    __shared__ float wt[32][DIM];
    __shared__ float hz[16][DIM];
    __shared__ float red[256];

    const int t  = threadIdx.x;
    const int i0 = blockIdx.x * 16;
    const int j  = t & 127;
    const int th = t >> 7;

    featsL[t] = pos_feat[i0 * LI + t];
    if (t < 64) featsL[256 + t] = pos_feat[i0 * LI + 256 + t];
    __syncthreads();

    float acc[8];
    for (int a = 0; a < 8; ++a) acc[a] = 0.f;

    for (int kt = 0; kt < 80; ++kt) {
        const int k0 = kt * 32;
        const int l  = k0 >> 7;
        const int d0 = k0 & 127;
        __syncthreads();  // protect xs/wt against previous iteration's readers
        {
            int e = t;
            int s = e >> 5, dd = e & 31;
            int f = featsL[s * LI + l];
            xs[s][dd] = ef_item[(size_t)f * DIM + d0 + dd];
            e = t + 256; s = e >> 5; dd = e & 31;
            f = featsL[s * LI + l];
            xs[s][dd] = ef_item[(size_t)f * DIM + d0 + dd];
        }
        for (int kh = 0; kh < 16; ++kh) {
            int kk = th + kh * 2;
            wt[kk][j] = enc_W[(size_t)(k0 + kk) * DIM + j];
        }
        __syncthreads();
        for (int kk = 0; kk < 32; ++kk) {
            float w = wt[kk][j];
            for (int a = 0; a < 8; ++a) acc[a] += xs[th * 8 + a][kk] * w;
        }
    }

    // h1 = relu(acc + enc_b)
    {
        float bj = enc_b[j];
        for (int a = 0; a < 8; ++a) {
            float h = acc[a] + bj;
            hz[th * 8 + a][j] = h > 0.f ? h : 0.f;
        }
    }
    __syncthreads();

    // mu / logvar
    float mu[8], lv[8];
    {
        float b1 = fc11_b[j], b2 = fc12_b[j];
        for (int a = 0; a < 8; ++a) { mu[a] = b1; lv[a] = b2; }
    }
    for (int d = 0; d < DIM; ++d) {
        float w1 = fc11_W[d * DIM + j];
        float w2 = fc12_W[d * DIM + j];
        for (int a = 0; a < 8; ++a) {
            float h = hz[th * 8 + a][d];
            mu[a] += h * w1;
            lv[a] += h * w2;
        }
    }
    __syncthreads();  // done reading hz (h1); safe to overwrite with z

    float kacc = 0.f;
    for (int a = 0; a < 8; ++a) {
        int s = th * 8 + a, i = i0 + s;
        float e = eps[(size_t)i * DIM + j];
        float zz = e * expf(0.5f * lv[a]) + mu[a];
        zbuf[(size_t)i * DIM + j] = zz;
        hz[s][j] = zz;
        kacc += 1.f + lv[a] - mu[a] * mu[a] - expf(lv[a]);
    }
    __syncthreads();

    // per-sample dots: z.pos_e, z.comp_e, sum (z - pos_e)^2
    const int s2 = t >> 4, tt = t & 15;
    const int i = i0 + s2;
    const size_t pbase = (size_t)pos_idx[i] * DIM;
    const size_t cbase = (size_t)comp_idx[i] * DIM;
    float zp = 0.f, zc = 0.f, zq = 0.f;
    for (int r = 0; r < 8; ++r) {
        int d = tt + r * 16;
        float zv = hz[s2][d];
        float pe = emb_item[pbase + d];
        float ce = emb_item[cbase + d];
        zp += zv * pe;
        zc += zv * ce;
        float dq = zv - pe;
        zq += dq * dq;
    }
    for (int m = 8; m >= 1; m >>= 1) {
        zp += __shfl_xor(zp, m, 64);
        zc += __shfl_xor(zc, m, 64);
        zq += __shfl_xor(zq, m, 64);
    }
    float contrib = 0.f;
    if (tt == 0) {
        float x = zp - zc;
        // log_sigmoid(x), numerically stable
        float ls = (x >= 0.f) ? -log1pf(expf(-x)) : (x - log1pf(expf(x)));
        contrib = -ls + zq;   // mmi term + (z-pos_e)^2 term
    }
    red[t] = -0.5f * kacc + contrib;
    __syncthreads();
    for (int off = 128; off > 0; off >>= 1) {
        if (t < off) red[t] += red[t + off];
        __syncthreads();
    }
    if (t == 0) k2part[blockIdx.x] = red[0];
}

// ---------------------------------------------------------------------------
// K3: decoder GEMM tile (16 samples x 256 cols) + mse partial.
// ---------------------------------------------------------------------------
__global__ __launch_bounds__(256) void k3_decoder(
    const int* __restrict__ pos_feat,
    const float* __restrict__ ef_item,
    const float* __restrict__ dec_W, const float* __restrict__ dec_b,
    const float* __restrict__ zbuf, float* __restrict__ k3part)
{
    __shared__ float zs[16][DIM];
    __shared__ int   feats2[16][2];
    __shared__ float red[256];

    const int t  = threadIdx.x;
    const int bs = blockIdx.x / 10;
    const int bc = blockIdx.x % 10;
    const int i0 = bs * 16;
    const int c0 = bc * 256;
    const int l0 = c0 >> 7;

    for (int q = 0; q < 8; ++q) {
        int e = t + q * 256;
        int s = e >> 7, d = e & 127;
        zs[s][d] = zbuf[(size_t)(i0 + s) * DIM + d];
    }
    if (t < 32) {
        int s = t >> 1, w = t & 1;
        feats2[s][w] = pos_feat[(i0 + s) * LI + l0 + w];
    }
    __syncthreads();

    const int colk = c0 + t;
    float acc[16];
    {
        float bk = dec_b[colk];
        for (int s = 0; s < 16; ++s) acc[s] = bk;
    }
    for (int d = 0; d < DIM; ++d) {
        float w = dec_W[(size_t)d * (LI * DIM) + colk];
        for (int s = 0; s < 16; ++s) acc[s] += zs[s][d] * w;
    }

    const int lw = t >> 7;
    const int dj = t & 127;
    float macc = 0.f;
    for (int s = 0; s < 16; ++s) {
        int f = feats2[s][lw];
        float xv = ef_item[(size_t)f * DIM + dj];
        float diff = acc[s] - xv;
        macc += diff * diff;
    }
    red[t] = macc;
    __syncthreads();
    for (int off = 128; off > 0; off >>= 1) {
        if (t < off) red[t] += red[t + off];
        __syncthreads();
    }
    if (t == 0) k3part[blockIdx.x] = red[0];
}

// ---------------------------------------------------------------------------
// K4: deterministic final reduction -> item_vae_loss scalar.
// ---------------------------------------------------------------------------
__global__ __launch_bounds__(256) void k4_final(
    const float* __restrict__ k2part, const float* __restrict__ k3part,
    float* __restrict__ out_scalar)
{
    __shared__ float red[256];
    const int t = threadIdx.x;
    float a = k2part[t];
    float b3 = 0.f;
    for (int q = t; q < 2560; q += 256) b3 += k3part[q];
    red[t] = a + 0.05f * b3;   // mse / LI  (LI = 20)
    __syncthreads();
    for (int off = 128; off > 0; off >>= 1) {
        if (t < off) red[t] += red[t + off];
        __syncthreads();
    }
    if (t == 0) out_scalar[0] = red[0];
}

// ---------------------------------------------------------------------------
extern "C" void kernel_launch(void* const* d_in, const int* in_sizes, int n_in,
                              void* d_out, int out_size, void* d_ws, size_t ws_size,
                              hipStream_t stream) {
    const int*   user_idx  = (const int*)d_in[0];
    const int*   user_feat = (const int*)d_in[1];
    const int*   pos_idx   = (const int*)d_in[2];
    const int*   pos_feat  = (const int*)d_in[3];
    const int*   neg_idx   = (const int*)d_in[4];
    const int*   neg_feat  = (const int*)d_in[5];
    const int*   comp_idx  = (const int*)d_in[6];
    const float* eps       = (const float*)d_in[7];
    const float* emb_user  = (const float*)d_in[8];
    const float* emb_item  = (const float*)d_in[9];
    const float* ef_user   = (const float*)d_in[10];
    const float* ef_item   = (const float*)d_in[11];
    const float* pop_u     = (const float*)d_in[12];
    const float* int_u     = (const float*)d_in[13];
    const float* pop_i     = (const float*)d_in[14];
    const float* int_i     = (const float*)d_in[15];
    const float* W_pop     = (const float*)d_in[16];
    const float* b_pop     = (const float*)d_in[17];
    const float* W_int     = (const float*)d_in[18];
    const float* b_int     = (const float*)d_in[19];
    const float* enc_W     = (const float*)d_in[20];
    const float* enc_b     = (const float*)d_in[21];
    const float* dec_W     = (const float*)d_in[22];
    const float* dec_b     = (const float*)d_in[23];
    const float* fc11_W    = (const float*)d_in[24];
    const float* fc11_b    = (const float*)d_in[25];
    const float* fc12_W    = (const float*)d_in[26];
    const float* fc12_b    = (const float*)d_in[27];

    float* out    = (float*)d_out;
    float* zbuf   = (float*)d_ws;                                   // B*D floats (2 MiB)
    float* k2part = (float*)((char*)d_ws + (size_t)BATCH * DIM * sizeof(float));
    float* k3part = k2part + 256;

    k1_branches<<<dim3(BATCH / 8), dim3(256), 0, stream>>>(
        user_idx, user_feat, pos_idx, pos_feat, neg_idx, neg_feat,
        emb_user, emb_item, ef_user, ef_item, pop_u, int_u, pop_i, int_i,
        W_pop, b_pop, W_int, b_int, out, out + BATCH);

    k2_encoder<<<dim3(BATCH / 16), dim3(256), 0, stream>>>(
        pos_feat, pos_idx, comp_idx, ef_item, emb_item, eps,
        enc_W, enc_b, fc11_W, fc11_b, fc12_W, fc12_b, zbuf, k2part);

    k3_decoder<<<dim3((BATCH / 16) * 10), dim3(256), 0, stream>>>(
        pos_feat, ef_item, dec_W, dec_b, zbuf, k3part);

    k4_final<<<dim3(1), dim3(256), 0, stream>>>(k2part, k3part, out + 2 * BATCH);
}

// Round 2
// 372.610 us; speedup vs baseline: 1.8832x; 1.8832x over previous
//
#include <hip/hip_runtime.h>
#include <math.h>

#define BATCH 4096
#define DIM 128
#define LU 10
#define LI 20

typedef float  f32x4  __attribute__((ext_vector_type(4)));
typedef short  s16x8  __attribute__((ext_vector_type(8)));

__device__ __forceinline__ float wave_reduce64(float v) {
    for (int m = 32; m >= 1; m >>= 1) v += __shfl_xor(v, m, 64);
    return v;
}

// round-to-nearest-even fp32 -> bf16
__device__ __forceinline__ short f2bf(float x) {
    unsigned u = __float_as_uint(x);
    u += 0x7FFFu + ((u >> 16) & 1u);
    return (short)(u >> 16);
}

// ---------------------------------------------------------------------------
// K0: prep — transpose+convert weights to bf16, convert ef_item to bf16.
//   blocks [0,320)    : encWT[128][2560]  = bf16(enc_W[k][j])
//   blocks [320,640)  : decWT[2560][128]  = bf16(dec_W[d][c])
//   blocks [640,656)  : fc11WT[128][128]  = bf16(fc11_W[k][j])
//   blocks [656,672)  : fc12WT[128][128]
//   blocks [672,1297) : ef16[5000*128]    = bf16(ef_item)
// ---------------------------------------------------------------------------
__global__ __launch_bounds__(256) void k0_prep(
    const float* __restrict__ enc_W, const float* __restrict__ dec_W,
    const float* __restrict__ fc11_W, const float* __restrict__ fc12_W,
    const float* __restrict__ ef_item,
    short* __restrict__ encWT, short* __restrict__ decWT,
    short* __restrict__ fc11WT, short* __restrict__ fc12WT,
    short* __restrict__ ef16)
{
    __shared__ float tile[32][33];
    const int b = blockIdx.x;
    const int t = threadIdx.x;

    if (b < 672) {
        const float* src; short* dst; int r0, c0, src_ld, dst_ld;
        if (b < 320) {           // enc_W [2560][128] -> encWT [128][2560]
            int tk = b % 80, tj = b / 80;
            src = enc_W; dst = encWT; r0 = tk * 32; c0 = tj * 32; src_ld = 128; dst_ld = 2560;
        } else if (b < 640) {    // dec_W [128][2560] -> decWT [2560][128]
            int tb = b - 320; int tc = tb % 80, td = tb / 80;
            src = dec_W; dst = decWT; r0 = td * 32; c0 = tc * 32; src_ld = 2560; dst_ld = 128;
        } else if (b < 656) {    // fc11
            int tb = b - 640; int tk = tb % 4, tj = tb / 4;
            src = fc11_W; dst = fc11WT; r0 = tk * 32; c0 = tj * 32; src_ld = 128; dst_ld = 128;
        } else {                 // fc12
            int tb = b - 656; int tk = tb % 4, tj = tb / 4;
            src = fc12_W; dst = fc12WT; r0 = tk * 32; c0 = tj * 32; src_ld = 128; dst_ld = 128;
        }
        for (int q = 0; q < 4; ++q) {
            int e = t + q * 256;
            int r = e >> 5, c = e & 31;
            tile[r][c] = src[(size_t)(r0 + r) * src_ld + (c0 + c)];
        }
        __syncthreads();
        for (int q = 0; q < 4; ++q) {
            int e = t + q * 256;
            int r = e >> 5, c = e & 31;   // output row = c0+r, col = r0+c
            dst[(size_t)(c0 + r) * dst_ld + (r0 + c)] = f2bf(tile[c][r]);
        }
    } else {
        int base = (b - 672) * 1024 + t * 4;
        float4 v = *(const float4*)(ef_item + base);
        short4 o;
        o.x = f2bf(v.x); o.y = f2bf(v.y); o.z = f2bf(v.z); o.w = f2bf(v.w);
        *(short4*)(ef16 + base) = o;
    }
}

// ---------------------------------------------------------------------------
// K1: branch attention + pooled@W + triplet losses. 8 samples per block.
// (unchanged this round)
// ---------------------------------------------------------------------------
__global__ __launch_bounds__(256) void k1_branches(
    const int* __restrict__ user_idx, const int* __restrict__ user_feat,
    const int* __restrict__ pos_idx, const int* __restrict__ pos_feat,
    const int* __restrict__ neg_idx, const int* __restrict__ neg_feat,
    const float* __restrict__ emb_user, const float* __restrict__ emb_item,
    const float* __restrict__ ef_user, const float* __restrict__ ef_item,
    const float* __restrict__ pop_u, const float* __restrict__ int_u,
    const float* __restrict__ pop_i, const float* __restrict__ int_i,
    const float* __restrict__ W_pop, const float* __restrict__ b_pop,
    const float* __restrict__ W_int, const float* __restrict__ b_int,
    float* __restrict__ out_hot, float* __restrict__ out_cold)
{
    __shared__ float fuse[LI + 1][DIM];
    __shared__ float pooled[8][2][DIM];
    __shared__ float sc[2][LI + 1];
    __shared__ float wgt[2][LI + 1];
    __shared__ int   smask[LI + 1];
    __shared__ float red[4][8];

    const int t    = threadIdx.x;
    const int s0   = blockIdx.x * 8;
    const int col  = t & 127;
    const int half = t >> 7;
    const int wv   = t >> 6;
    const int lid  = t & 63;

    float ures[8], pres[8], nres[8];

    for (int b = 0; b < 3; ++b) {
        for (int s = 0; s < 8; ++s) {
            const int i = s0 + s;
            int L, idx;
            const int* feats;
            const float* etab;
            const float* ftab;
            if (b == 0)      { L = LU; idx = user_idx[i]; feats = user_feat + i * LU; etab = emb_user; ftab = ef_user; }
            else if (b == 1) { L = LI; idx = pos_idx[i];  feats = pos_feat + i * LI;  etab = emb_item; ftab = ef_item; }
            else             { L = LI; idx = neg_idx[i];  feats = neg_feat + i * LI;  etab = emb_item; ftab = ef_item; }

            for (int r = half; r <= L; r += 2) {
                float v; int m;
                if (r == 0) { v = etab[(size_t)idx * DIM + col]; m = 1; }
                else        { int f = feats[r - 1]; m = f; v = ftab[(size_t)f * DIM + col]; }
                fuse[r][col] = v;
                if (col == 0) smask[r] = m;
            }
            __syncthreads();

            const float* vec = (b == 0) ? ((wv < 2) ? pop_u : int_u)
                                        : ((wv < 2) ? pop_i : int_i);
            float v0 = vec[lid], v1 = vec[lid + 64];
            for (int l = (wv & 1); l <= L; l += 2) {
                float p = fuse[l][lid] * v0 + fuse[l][lid + 64] * v1;
                p = wave_reduce64(p);
                if (lid == 0) sc[wv >> 1][l] = p;
            }
            __syncthreads();

            if (t < 2) {
                float m = -1e30f;
                for (int l = 0; l <= L; ++l)
                    if (smask[l] != 0) m = fmaxf(m, sc[t][l]);
                float ssum = 0.f;
                for (int l = 0; l <= L; ++l) {
                    float e = (smask[l] != 0) ? expf(sc[t][l] - m) : 0.f;
                    wgt[t][l] = e;
                    ssum += e;
                }
                float r = 1.f / ssum;
                for (int l = 0; l <= L; ++l) wgt[t][l] *= r;
            }
            __syncthreads();

            float acc = 0.f;
            for (int l = 0; l <= L; ++l) acc += wgt[half][l] * fuse[l][col];
            pooled[s][half][col] = acc;
            __syncthreads();
        }

        const float* W    = half ? W_int : W_pop;
        const float* bias = half ? b_int : b_pop;
        float acc[8];
        {
            float bj = bias[col];
            for (int s = 0; s < 8; ++s) acc[s] = bj;
        }
        for (int d = 0; d < DIM; ++d) {
            float w = W[d * DIM + col];
            for (int s = 0; s < 8; ++s) acc[s] += pooled[s][half][d] * w;
        }
        if (b == 0)      for (int s = 0; s < 8; ++s) ures[s] = acc[s];
        else if (b == 1) for (int s = 0; s < 8; ++s) pres[s] = acc[s];
        else             for (int s = 0; s < 8; ++s) nres[s] = acc[s];
        __syncthreads();
    }

    float part[8];
    for (int s = 0; s < 8; ++s) {
        float dp = ures[s] - pres[s];
        float dn = ures[s] - nres[s];
        part[s] = dp * dp - dn * dn;
    }
    for (int s = 0; s < 8; ++s) part[s] = wave_reduce64(part[s]);
    if (lid == 0)
        for (int s = 0; s < 8; ++s) red[wv][s] = part[s];
    __syncthreads();
    if (t < 8) {
        float v = red[0][t] + red[1][t] + 1.0f;
        out_hot[s0 + t] = v > 0.f ? v : 0.f;
    } else if (t < 16) {
        int s = t - 8;
        float v = red[2][s] + red[3][s] + 1.0f;
        out_cold[s0 + s] = v > 0.f ? v : 0.f;
    }
}

// ---------------------------------------------------------------------------
// K2: MFMA encoder + mu/lv + z + kld/mmi/zsq partials. 16 samples per block,
// 4 waves; each wave owns 32 output cols. Operands streamed from L2 (no LDS
// staging of GEMM tiles, no barriers in the K-loop).
// ---------------------------------------------------------------------------
__global__ __launch_bounds__(256) void k2_mfma(
    const int* __restrict__ pos_feat, const int* __restrict__ pos_idx,
    const int* __restrict__ comp_idx,
    const float* __restrict__ emb_item, const float* __restrict__ eps,
    const float* __restrict__ enc_b,
    const float* __restrict__ fc11_b, const float* __restrict__ fc12_b,
    const short* __restrict__ encWT, const short* __restrict__ fc11WT,
    const short* __restrict__ fc12WT, const short* __restrict__ ef16,
    short* __restrict__ zbuf, float* __restrict__ k2part)
{
    __shared__ int   featsL[16 * LI];
    __shared__ int   spi[16], sci[16];
    __shared__ __align__(16) short hlds[16 * 128];
    __shared__ float sdots[4][16][3];
    __shared__ float red[256];

    const int t    = threadIdx.x;
    const int i0   = blockIdx.x * 16;
    const int w    = t >> 6;
    const int lane = t & 63;
    const int g    = lane >> 4;      // k-group / row-group
    const int q    = lane & 15;      // A-row (= sample) and B-col-within-frag

    if (t < 16)                 spi[t] = pos_idx[i0 + t];
    else if (t < 32)            sci[t - 16] = comp_idx[i0 + t - 16];
    if (t < 320 - 64) { }  // (filler to keep branch simple)
    {
        // load 320 feature ids
        if (t < 256) featsL[t] = pos_feat[i0 * LI + t];
        if (t < 64)  featsL[256 + t] = pos_feat[i0 * LI + 256 + t];
    }
    __syncthreads();

    // ---- encoder GEMM: h1[16][128] = relu(X @ enc_W + b) ------------------
    const int j0 = w * 32 + q;        // frag0 col
    const int j1 = j0 + 16;           // frag1 col
    const short* bbase0 = encWT + (size_t)j0 * 2560 + g * 8;
    const short* bbase1 = encWT + (size_t)j1 * 2560 + g * 8;

    f32x4 acc0 = {0.f, 0.f, 0.f, 0.f};
    f32x4 acc1 = {0.f, 0.f, 0.f, 0.f};

    for (int l = 0; l < LI; ++l) {
        const int f = featsL[q * LI + l];
        const short* arow = ef16 + (size_t)f * DIM + g * 8;
#pragma unroll
        for (int dt = 0; dt < 4; ++dt) {
            const int koff = l * 128 + dt * 32;
            s16x8 a  = *(const s16x8*)(arow + dt * 32);
            s16x8 b0 = *(const s16x8*)(bbase0 + koff);
            s16x8 b1 = *(const s16x8*)(bbase1 + koff);
            acc0 = __builtin_amdgcn_mfma_f32_16x16x32_bf16(a, b0, acc0, 0, 0, 0);
            acc1 = __builtin_amdgcn_mfma_f32_16x16x32_bf16(a, b1, acc1, 0, 0, 0);
        }
    }

    // bias + relu, store h1 (bf16) to swizzled LDS
    {
        float eb0 = enc_b[j0], eb1 = enc_b[j1];
#pragma unroll
        for (int r = 0; r < 4; ++r) {
            int s = g * 4 + r;
            float h0 = acc0[r] + eb0; h0 = h0 > 0.f ? h0 : 0.f;
            float h1 = acc1[r] + eb1; h1 = h1 > 0.f ? h1 : 0.f;
            int swz = (s & 7) << 3;   // XOR on short-index bits 3..5 (byte bits 4..6)
            hlds[(s * 128 + j0) ^ swz] = f2bf(h0);
            hlds[(s * 128 + j1) ^ swz] = f2bf(h1);
        }
    }
    __syncthreads();

    // ---- mu / logvar GEMMs (K=128) ----------------------------------------
    const short* fb0_11 = fc11WT + (size_t)j0 * DIM + g * 8;
    const short* fb1_11 = fc11WT + (size_t)j1 * DIM + g * 8;
    const short* fb0_12 = fc12WT + (size_t)j0 * DIM + g * 8;
    const short* fb1_12 = fc12WT + (size_t)j1 * DIM + g * 8;

    f32x4 mu0 = {0.f,0.f,0.f,0.f}, mu1 = {0.f,0.f,0.f,0.f};
    f32x4 lv0 = {0.f,0.f,0.f,0.f}, lv1 = {0.f,0.f,0.f,0.f};
#pragma unroll
    for (int kt = 0; kt < 4; ++kt) {
        int sidx = (q * 128 + kt * 32 + g * 8) ^ ((q & 7) << 3);
        s16x8 a = *(const s16x8*)&hlds[sidx];
        s16x8 w11a = *(const s16x8*)(fb0_11 + kt * 32);
        s16x8 w11b = *(const s16x8*)(fb1_11 + kt * 32);
        s16x8 w12a = *(const s16x8*)(fb0_12 + kt * 32);
        s16x8 w12b = *(const s16x8*)(fb1_12 + kt * 32);
        mu0 = __builtin_amdgcn_mfma_f32_16x16x32_bf16(a, w11a, mu0, 0, 0, 0);
        mu1 = __builtin_amdgcn_mfma_f32_16x16x32_bf16(a, w11b, mu1, 0, 0, 0);
        lv0 = __builtin_amdgcn_mfma_f32_16x16x32_bf16(a, w12a, lv0, 0, 0, 0);
        lv1 = __builtin_amdgcn_mfma_f32_16x16x32_bf16(a, w12b, lv1, 0, 0, 0);
    }

    // ---- z, kld, per-sample dot partials ----------------------------------
    float b11_0 = fc11_b[j0], b11_1 = fc11_b[j1];
    float b12_0 = fc12_b[j0], b12_1 = fc12_b[j1];

    float kacc = 0.f;
#pragma unroll
    for (int r = 0; r < 4; ++r) {
        const int s = g * 4 + r;
        const int i = i0 + s;
        float m0 = mu0[r] + b11_0, m1 = mu1[r] + b11_1;
        float v0 = lv0[r] + b12_0, v1 = lv1[r] + b12_1;
        float e0 = eps[(size_t)i * DIM + j0];
        float e1 = eps[(size_t)i * DIM + j1];
        float z0 = e0 * expf(0.5f * v0) + m0;
        float z1 = e1 * expf(0.5f * v1) + m1;
        zbuf[(size_t)i * DIM + j0] = f2bf(z0);
        zbuf[(size_t)i * DIM + j1] = f2bf(z1);
        kacc += (1.f + v0 - m0 * m0 - expf(v0)) + (1.f + v1 - m1 * m1 - expf(v1));

        const size_t pb = (size_t)spi[s] * DIM;
        const size_t cb = (size_t)sci[s] * DIM;
        float pe0 = emb_item[pb + j0], pe1 = emb_item[pb + j1];
        float ce0 = emb_item[cb + j0], ce1 = emb_item[cb + j1];
        float zp = z0 * pe0 + z1 * pe1;
        float zc = z0 * ce0 + z1 * ce1;
        float d0 = z0 - pe0, d1 = z1 - pe1;
        float zq = d0 * d0 + d1 * d1;
        for (int m = 8; m >= 1; m >>= 1) {
            zp += __shfl_xor(zp, m, 64);
            zc += __shfl_xor(zc, m, 64);
            zq += __shfl_xor(zq, m, 64);
        }
        if (q == 0) {
            sdots[w][s][0] = zp;
            sdots[w][s][1] = zc;
            sdots[w][s][2] = zq;
        }
    }

    red[t] = -0.5f * kacc;
    __syncthreads();

    if (t < 16) {
        float zp = 0.f, zc = 0.f, zq = 0.f;
        for (int ww = 0; ww < 4; ++ww) {
            zp += sdots[ww][t][0];
            zc += sdots[ww][t][1];
            zq += sdots[ww][t][2];
        }
        float x = zp - zc;
        float ls = (x >= 0.f) ? -log1pf(expf(-x)) : (x - log1pf(expf(x)));
        red[t] += -ls + zq;
    }
    __syncthreads();
    for (int off = 128; off > 0; off >>= 1) {
        if (t < off) red[t] += red[t + off];
        __syncthreads();
    }
    if (t == 0) k2part[blockIdx.x] = red[0];
}

// ---------------------------------------------------------------------------
// K3: MFMA decoder -> mse partial only. 16 samples per block; each wave owns
// 640 output cols (40 16-col frags), K=128 from zbuf (bf16).
// ---------------------------------------------------------------------------
__global__ __launch_bounds__(256) void k3_mfma(
    const int* __restrict__ pos_feat,
    const float* __restrict__ ef_item, const float* __restrict__ dec_b,
    const short* __restrict__ decWT, const short* __restrict__ zbuf,
    float* __restrict__ k3part)
{
    __shared__ int   featsL[16 * LI];
    __shared__ float red[256];

    const int t    = threadIdx.x;
    const int i0   = blockIdx.x * 16;
    const int w    = t >> 6;
    const int lane = t & 63;
    const int g    = lane >> 4;
    const int q    = lane & 15;

    if (t < 256) featsL[t] = pos_feat[i0 * LI + t];
    if (t < 64)  featsL[256 + t] = pos_feat[i0 * LI + 256 + t];
    __syncthreads();

    // A-fragments: z rows, 4 K-steps, loaded once
    s16x8 za[4];
#pragma unroll
    for (int kt = 0; kt < 4; ++kt)
        za[kt] = *(const s16x8*)(zbuf + (size_t)(i0 + q) * DIM + kt * 32 + g * 8);

    float macc = 0.f;
    for (int fr = 0; fr < 40; ++fr) {
        const int c = w * 640 + fr * 16 + q;      // output col for this lane
        const short* bb = decWT + (size_t)c * DIM + g * 8;
        f32x4 acc = {0.f, 0.f, 0.f, 0.f};
#pragma unroll
        for (int kt = 0; kt < 4; ++kt) {
            s16x8 b = *(const s16x8*)(bb + kt * 32);
            acc = __builtin_amdgcn_mfma_f32_16x16x32_bf16(za[kt], b, acc, 0, 0, 0);
        }
        const float bias = dec_b[c];
        const int l = c >> 7, d = c & 127;
#pragma unroll
        for (int r = 0; r < 4; ++r) {
            const int s = g * 4 + r;
            const int f = featsL[s * LI + l];
            float x = ef_item[(size_t)f * DIM + d];
            float diff = acc[r] + bias - x;
            macc += diff * diff;
        }
    }

    red[t] = macc;
    __syncthreads();
    for (int off = 128; off > 0; off >>= 1) {
        if (t < off) red[t] += red[t + off];
        __syncthreads();
    }
    if (t == 0) k3part[blockIdx.x] = red[0];
}

// ---------------------------------------------------------------------------
// K4: final reduction -> item_vae_loss scalar.
// ---------------------------------------------------------------------------
__global__ __launch_bounds__(256) void k4_final(
    const float* __restrict__ k2part, const float* __restrict__ k3part,
    float* __restrict__ out_scalar)
{
    __shared__ float red[256];
    const int t = threadIdx.x;
    red[t] = k2part[t] + 0.05f * k3part[t];   // mse / LI  (LI = 20)
    __syncthreads();
    for (int off = 128; off > 0; off >>= 1) {
        if (t < off) red[t] += red[t + off];
        __syncthreads();
    }
    if (t == 0) out_scalar[0] = red[0];
}

// ---------------------------------------------------------------------------
extern "C" void kernel_launch(void* const* d_in, const int* in_sizes, int n_in,
                              void* d_out, int out_size, void* d_ws, size_t ws_size,
                              hipStream_t stream) {
    const int*   user_idx  = (const int*)d_in[0];
    const int*   user_feat = (const int*)d_in[1];
    const int*   pos_idx   = (const int*)d_in[2];
    const int*   pos_feat  = (const int*)d_in[3];
    const int*   neg_idx   = (const int*)d_in[4];
    const int*   neg_feat  = (const int*)d_in[5];
    const int*   comp_idx  = (const int*)d_in[6];
    const float* eps       = (const float*)d_in[7];
    const float* emb_user  = (const float*)d_in[8];
    const float* emb_item  = (const float*)d_in[9];
    const float* ef_user   = (const float*)d_in[10];
    const float* ef_item   = (const float*)d_in[11];
    const float* pop_u     = (const float*)d_in[12];
    const float* int_u     = (const float*)d_in[13];
    const float* pop_i     = (const float*)d_in[14];
    const float* int_i     = (const float*)d_in[15];
    const float* W_pop     = (const float*)d_in[16];
    const float* b_pop     = (const float*)d_in[17];
    const float* W_int     = (const float*)d_in[18];
    const float* b_int     = (const float*)d_in[19];
    const float* enc_W     = (const float*)d_in[20];
    const float* enc_b     = (const float*)d_in[21];
    const float* dec_W     = (const float*)d_in[22];
    const float* dec_b     = (const float*)d_in[23];
    const float* fc11_W    = (const float*)d_in[24];
    const float* fc11_b    = (const float*)d_in[25];
    const float* fc12_W    = (const float*)d_in[26];
    const float* fc12_b    = (const float*)d_in[27];

    float* out = (float*)d_out;
    char*  ws  = (char*)d_ws;

    short* zbuf   = (short*)(ws);                       // 4096*128*2      = 1,048,576
    short* encWT  = (short*)(ws + 1048576);             // 128*2560*2      =   655,360
    short* decWT  = (short*)(ws + 1703936);             // 2560*128*2      =   655,360
    short* fc11WT = (short*)(ws + 2359296);             // 128*128*2       =    32,768
    short* fc12WT = (short*)(ws + 2392064);             // 128*128*2       =    32,768
    short* ef16   = (short*)(ws + 2424832);             // 5000*128*2      = 1,280,000
    float* k2part = (float*)(ws + 3704832);             // 256*4
    float* k3part = (float*)(ws + 3705856);             // 256*4

    k0_prep<<<dim3(1297), dim3(256), 0, stream>>>(
        enc_W, dec_W, fc11_W, fc12_W, ef_item,
        encWT, decWT, fc11WT, fc12WT, ef16);

    k1_branches<<<dim3(BATCH / 8), dim3(256), 0, stream>>>(
        user_idx, user_feat, pos_idx, pos_feat, neg_idx, neg_feat,
        emb_user, emb_item, ef_user, ef_item, pop_u, int_u, pop_i, int_i,
        W_pop, b_pop, W_int, b_int, out, out + BATCH);

    k2_mfma<<<dim3(BATCH / 16), dim3(256), 0, stream>>>(
        pos_feat, pos_idx, comp_idx, emb_item, eps,
        enc_b, fc11_b, fc12_b, encWT, fc11WT, fc12WT, ef16,
        zbuf, k2part);

    k3_mfma<<<dim3(BATCH / 16), dim3(256), 0, stream>>>(
        pos_feat, ef_item, dec_b, decWT, zbuf, k3part);

    k4_final<<<dim3(1), dim3(256), 0, stream>>>(k2part, k3part, out + 2 * BATCH);
}

// Round 3
// 149.103 us; speedup vs baseline: 4.7061x; 2.4990x over previous
//
#include <hip/hip_runtime.h>
#include <math.h>

#define BATCH 4096
#define DIM 128
#define LU 10
#define LI 20

typedef float  f32x4  __attribute__((ext_vector_type(4)));
typedef short  s16x8  __attribute__((ext_vector_type(8)));

// round-to-nearest-even fp32 -> bf16
__device__ __forceinline__ short f2bf(float x) {
    unsigned u = __float_as_uint(x);
    u += 0x7FFFu + ((u >> 16) & 1u);
    return (short)(u >> 16);
}

// ---------------------------------------------------------------------------
// K0: prep — transpose+convert weights to bf16, convert ef_item to bf16.
//   blocks [0,320)     : encWT[128][2560]  = bf16(enc_W[k][j])
//   blocks [320,640)   : decWT[2560][128]  = bf16(dec_W[d][c])
//   blocks [640,656)   : fc11WT[128][128]
//   blocks [656,672)   : fc12WT[128][128]
//   blocks [672,688)   : wpopT[128][128]   = bf16(W_pop[k][j])
//   blocks [688,704)   : wintT[128][128]
//   blocks [704,1329)  : ef16[5000*128]    = bf16(ef_item)
// ---------------------------------------------------------------------------
__global__ __launch_bounds__(256) void k0_prep(
    const float* __restrict__ enc_W, const float* __restrict__ dec_W,
    const float* __restrict__ fc11_W, const float* __restrict__ fc12_W,
    const float* __restrict__ W_pop, const float* __restrict__ W_int,
    const float* __restrict__ ef_item,
    short* __restrict__ encWT, short* __restrict__ decWT,
    short* __restrict__ fc11WT, short* __restrict__ fc12WT,
    short* __restrict__ wpopT, short* __restrict__ wintT,
    short* __restrict__ ef16)
{
    __shared__ float tile[32][33];
    const int b = blockIdx.x;
    const int t = threadIdx.x;

    if (b < 704) {
        const float* src; short* dst; int r0, c0, src_ld, dst_ld;
        if (b < 320) {           // enc_W [2560][128] -> encWT [128][2560]
            int tk = b % 80, tj = b / 80;
            src = enc_W; dst = encWT; r0 = tk * 32; c0 = tj * 32; src_ld = 128; dst_ld = 2560;
        } else if (b < 640) {    // dec_W [128][2560] -> decWT [2560][128]
            int tb = b - 320; int tc = tb % 80, td = tb / 80;
            src = dec_W; dst = decWT; r0 = td * 32; c0 = tc * 32; src_ld = 2560; dst_ld = 128;
        } else if (b < 656) {
            int tb = b - 640; int tk = tb % 4, tj = tb / 4;
            src = fc11_W; dst = fc11WT; r0 = tk * 32; c0 = tj * 32; src_ld = 128; dst_ld = 128;
        } else if (b < 672) {
            int tb = b - 656; int tk = tb % 4, tj = tb / 4;
            src = fc12_W; dst = fc12WT; r0 = tk * 32; c0 = tj * 32; src_ld = 128; dst_ld = 128;
        } else if (b < 688) {
            int tb = b - 672; int tk = tb % 4, tj = tb / 4;
            src = W_pop; dst = wpopT; r0 = tk * 32; c0 = tj * 32; src_ld = 128; dst_ld = 128;
        } else {
            int tb = b - 688; int tk = tb % 4, tj = tb / 4;
            src = W_int; dst = wintT; r0 = tk * 32; c0 = tj * 32; src_ld = 128; dst_ld = 128;
        }
        for (int q = 0; q < 4; ++q) {
            int e = t + q * 256;
            int r = e >> 5, c = e & 31;
            tile[r][c] = src[(size_t)(r0 + r) * src_ld + (c0 + c)];
        }
        __syncthreads();
        for (int q = 0; q < 4; ++q) {
            int e = t + q * 256;
            int r = e >> 5, c = e & 31;
            dst[(size_t)(c0 + r) * dst_ld + (r0 + c)] = f2bf(tile[c][r]);
        }
    } else {
        int base = (b - 704) * 1024 + t * 4;
        float4 v = *(const float4*)(ef_item + base);
        short4 o;
        o.x = f2bf(v.x); o.y = f2bf(v.y); o.z = f2bf(v.z); o.w = f2bf(v.w);
        *(short4*)(ef16 + base) = o;
    }
}

// ---------------------------------------------------------------------------
// K1a: attention pooling, barrier-free. Each 32-lane half-wave handles one
// sample: lane owns 4 dims (float4). Scores reduced by 5-round shuffle
// butterfly within the half; softmax computed redundantly per lane; rows
// reloaded (L2-hot) for pooling. Templated on L for static unrolling.
// ---------------------------------------------------------------------------
template<int L>
__global__ __launch_bounds__(256) void k1a_pool(
    const int* __restrict__ idxp, const int* __restrict__ featp,
    const float* __restrict__ etab, const float* __restrict__ ftab,
    const float* __restrict__ vpop, const float* __restrict__ vint,
    float* __restrict__ poolH, float* __restrict__ poolC)
{
    const int t   = threadIdx.x;
    const int w   = t >> 6;
    const int lid = t & 63;
    const int h2  = lid >> 5;
    const int j32 = lid & 31;
    const int i   = (blockIdx.x * 4 + w) * 2 + h2;
    const int d   = j32 * 4;

    const float4 vp = *(const float4*)(vpop + d);
    const float4 vi = *(const float4*)(vint + d);

    const int idx = idxp[i];
    const float4 f0 = *(const float4*)(etab + (size_t)idx * DIM + d);

    float sp[L + 1], si[L + 1];
    sp[0] = f0.x * vp.x + f0.y * vp.y + f0.z * vp.z + f0.w * vp.w;
    si[0] = f0.x * vi.x + f0.y * vi.y + f0.z * vi.z + f0.w * vi.w;

    unsigned mbits = 1u;
    int fidx[L];
#pragma unroll
    for (int l = 0; l < L; ++l) {
        int f = featp[i * L + l];
        fidx[l] = f;
        mbits |= (f != 0 ? 2u : 0u) << l;
        float4 fv = *(const float4*)(ftab + (size_t)f * DIM + d);
        sp[l + 1] = fv.x * vp.x + fv.y * vp.y + fv.z * vp.z + fv.w * vp.w;
        si[l + 1] = fv.x * vi.x + fv.y * vi.y + fv.z * vi.z + fv.w * vi.w;
    }

    // butterfly reduce over the 32 lanes of this half (masks stay in-half)
#pragma unroll
    for (int l = 0; l <= L; ++l) {
        float a = sp[l], b = si[l];
        for (int m = 16; m >= 1; m >>= 1) {
            a += __shfl_xor(a, m, 64);
            b += __shfl_xor(b, m, 64);
        }
        sp[l] = a; si[l] = b;
    }

    // softmax over valid rows (redundant per lane; mbits uniform per half)
    float mh = sp[0], mc = si[0];
#pragma unroll
    for (int l = 1; l <= L; ++l) {
        bool v = (mbits >> l) & 1u;
        mh = v ? fmaxf(mh, sp[l]) : mh;
        mc = v ? fmaxf(mc, si[l]) : mc;
    }
    float sh = 0.f, sc = 0.f;
#pragma unroll
    for (int l = 0; l <= L; ++l) {
        bool v = (mbits >> l) & 1u;
        float eh = v ? __expf(sp[l] - mh) : 0.f;
        float ec = v ? __expf(si[l] - mc) : 0.f;
        sp[l] = eh; si[l] = ec;
        sh += eh; sc += ec;
    }
    const float rh = 1.f / sh, rc = 1.f / sc;

    // pooling: reload rows (L2-hot), weighted sum over rows
    float phx = sp[0] * f0.x, phy = sp[0] * f0.y, phz = sp[0] * f0.z, phw = sp[0] * f0.w;
    float pcx = si[0] * f0.x, pcy = si[0] * f0.y, pcz = si[0] * f0.z, pcw = si[0] * f0.w;
#pragma unroll
    for (int l = 0; l < L; ++l) {
        float4 fv = *(const float4*)(ftab + (size_t)fidx[l] * DIM + d);
        float wh = sp[l + 1], wc = si[l + 1];
        phx += wh * fv.x; phy += wh * fv.y; phz += wh * fv.z; phw += wh * fv.w;
        pcx += wc * fv.x; pcy += wc * fv.y; pcz += wc * fv.z; pcw += wc * fv.w;
    }
    float4 rH; rH.x = phx * rh; rH.y = phy * rh; rH.z = phz * rh; rH.w = phw * rh;
    float4 rC; rC.x = pcx * rc; rC.y = pcy * rc; rC.z = pcz * rc; rC.w = pcw * rc;
    *(float4*)(poolH + (size_t)i * DIM + d) = rH;
    *(float4*)(poolC + (size_t)i * DIM + d) = rC;
}

// ---------------------------------------------------------------------------
// K1b: triplet losses via MFMA. Biases cancel in differences:
//   u_hot - p_hot = (pool_u - pool_p) @ W_pop.
// 16 samples per block; wave w computes one diff-matrix GEMM [16x128]@[128x128]
// and its per-row squared sums. w: 0=hot/pos 1=hot/neg 2=cold/pos 3=cold/neg.
// ---------------------------------------------------------------------------
__global__ __launch_bounds__(256) void k1b_loss(
    const float* __restrict__ pooled, const short* __restrict__ wpopT,
    const short* __restrict__ wintT,
    float* __restrict__ out_hot, float* __restrict__ out_cold)
{
    __shared__ float sArr[4][16];
    const int t    = threadIdx.x;
    const int w    = t >> 6;
    const int lane = t & 63;
    const int g    = lane >> 4;
    const int q    = lane & 15;
    const int i0   = blockIdx.x * 16;

    const int h     = w >> 1;        // 0 hot, 1 cold
    const int other = (w & 1) + 1;   // 1 pos, 2 neg
    const float* pu = pooled + (size_t)(0 * 2 + h) * BATCH * DIM;
    const float* po = pooled + (size_t)(other * 2 + h) * BATCH * DIM;
    const short* wT = h ? wintT : wpopT;

    // A fragments: diff rows in bf16
    s16x8 afr[4];
#pragma unroll
    for (int kt = 0; kt < 4; ++kt) {
        const size_t off = (size_t)(i0 + q) * DIM + kt * 32 + g * 8;
        f32x4 ua = *(const f32x4*)(pu + off);
        f32x4 ub = *(const f32x4*)(pu + off + 4);
        f32x4 oa = *(const f32x4*)(po + off);
        f32x4 ob = *(const f32x4*)(po + off + 4);
        s16x8 v;
        v[0] = f2bf(ua[0] - oa[0]); v[1] = f2bf(ua[1] - oa[1]);
        v[2] = f2bf(ua[2] - oa[2]); v[3] = f2bf(ua[3] - oa[3]);
        v[4] = f2bf(ub[0] - ob[0]); v[5] = f2bf(ub[1] - ob[1]);
        v[6] = f2bf(ub[2] - ob[2]); v[7] = f2bf(ub[3] - ob[3]);
        afr[kt] = v;
    }

    float sq0 = 0.f, sq1 = 0.f, sq2 = 0.f, sq3 = 0.f;
    for (int fr = 0; fr < 8; ++fr) {
        const short* bb = wT + (size_t)(fr * 16 + q) * DIM + g * 8;
        f32x4 acc = {0.f, 0.f, 0.f, 0.f};
#pragma unroll
        for (int kt = 0; kt < 4; ++kt) {
            s16x8 bfr = *(const s16x8*)(bb + kt * 32);
            acc = __builtin_amdgcn_mfma_f32_16x16x32_bf16(afr[kt], bfr, acc, 0, 0, 0);
        }
        sq0 += acc[0] * acc[0]; sq1 += acc[1] * acc[1];
        sq2 += acc[2] * acc[2]; sq3 += acc[3] * acc[3];
    }
    // reduce over the 16 cols held by q-lanes
    for (int m = 8; m >= 1; m >>= 1) {
        sq0 += __shfl_xor(sq0, m, 64);
        sq1 += __shfl_xor(sq1, m, 64);
        sq2 += __shfl_xor(sq2, m, 64);
        sq3 += __shfl_xor(sq3, m, 64);
    }
    if (q == 0) {
        sArr[w][g * 4 + 0] = sq0;
        sArr[w][g * 4 + 1] = sq1;
        sArr[w][g * 4 + 2] = sq2;
        sArr[w][g * 4 + 3] = sq3;
    }
    __syncthreads();
    if (t < 16) {
        float v = sArr[0][t] - sArr[1][t] + 1.0f;
        out_hot[i0 + t] = v > 0.f ? v : 0.f;
    } else if (t < 32) {
        int s = t - 16;
        float v = sArr[2][s] - sArr[3][s] + 1.0f;
        out_cold[i0 + s] = v > 0.f ? v : 0.f;
    }
}

// ---------------------------------------------------------------------------
// K2: MFMA encoder + mu/lv + z + kld/mmi/zsq partials. (unchanged)
// ---------------------------------------------------------------------------
__global__ __launch_bounds__(256) void k2_mfma(
    const int* __restrict__ pos_feat, const int* __restrict__ pos_idx,
    const int* __restrict__ comp_idx,
    const float* __restrict__ emb_item, const float* __restrict__ eps,
    const float* __restrict__ enc_b,
    const float* __restrict__ fc11_b, const float* __restrict__ fc12_b,
    const short* __restrict__ encWT, const short* __restrict__ fc11WT,
    const short* __restrict__ fc12WT, const short* __restrict__ ef16,
    short* __restrict__ zbuf, float* __restrict__ k2part)
{
    __shared__ int   featsL[16 * LI];
    __shared__ int   spi[16], sci[16];
    __shared__ __align__(16) short hlds[16 * 128];
    __shared__ float sdots[4][16][3];
    __shared__ float red[256];

    const int t    = threadIdx.x;
    const int i0   = blockIdx.x * 16;
    const int w    = t >> 6;
    const int lane = t & 63;
    const int g    = lane >> 4;
    const int q    = lane & 15;

    if (t < 16)      spi[t] = pos_idx[i0 + t];
    else if (t < 32) sci[t - 16] = comp_idx[i0 + t - 16];
    if (t < 256) featsL[t] = pos_feat[i0 * LI + t];
    if (t < 64)  featsL[256 + t] = pos_feat[i0 * LI + 256 + t];
    __syncthreads();

    const int j0 = w * 32 + q;
    const int j1 = j0 + 16;
    const short* bbase0 = encWT + (size_t)j0 * 2560 + g * 8;
    const short* bbase1 = encWT + (size_t)j1 * 2560 + g * 8;

    f32x4 acc0 = {0.f, 0.f, 0.f, 0.f};
    f32x4 acc1 = {0.f, 0.f, 0.f, 0.f};

    for (int l = 0; l < LI; ++l) {
        const int f = featsL[q * LI + l];
        const short* arow = ef16 + (size_t)f * DIM + g * 8;
#pragma unroll
        for (int dt = 0; dt < 4; ++dt) {
            const int koff = l * 128 + dt * 32;
            s16x8 a  = *(const s16x8*)(arow + dt * 32);
            s16x8 b0 = *(const s16x8*)(bbase0 + koff);
            s16x8 b1 = *(const s16x8*)(bbase1 + koff);
            acc0 = __builtin_amdgcn_mfma_f32_16x16x32_bf16(a, b0, acc0, 0, 0, 0);
            acc1 = __builtin_amdgcn_mfma_f32_16x16x32_bf16(a, b1, acc1, 0, 0, 0);
        }
    }

    {
        float eb0 = enc_b[j0], eb1 = enc_b[j1];
#pragma unroll
        for (int r = 0; r < 4; ++r) {
            int s = g * 4 + r;
            float h0 = acc0[r] + eb0; h0 = h0 > 0.f ? h0 : 0.f;
            float h1 = acc1[r] + eb1; h1 = h1 > 0.f ? h1 : 0.f;
            int swz = (s & 7) << 3;
            hlds[(s * 128 + j0) ^ swz] = f2bf(h0);
            hlds[(s * 128 + j1) ^ swz] = f2bf(h1);
        }
    }
    __syncthreads();

    const short* fb0_11 = fc11WT + (size_t)j0 * DIM + g * 8;
    const short* fb1_11 = fc11WT + (size_t)j1 * DIM + g * 8;
    const short* fb0_12 = fc12WT + (size_t)j0 * DIM + g * 8;
    const short* fb1_12 = fc12WT + (size_t)j1 * DIM + g * 8;

    f32x4 mu0 = {0.f,0.f,0.f,0.f}, mu1 = {0.f,0.f,0.f,0.f};
    f32x4 lv0 = {0.f,0.f,0.f,0.f}, lv1 = {0.f,0.f,0.f,0.f};
#pragma unroll
    for (int kt = 0; kt < 4; ++kt) {
        int sidx = (q * 128 + kt * 32 + g * 8) ^ ((q & 7) << 3);
        s16x8 a = *(const s16x8*)&hlds[sidx];
        s16x8 w11a = *(const s16x8*)(fb0_11 + kt * 32);
        s16x8 w11b = *(const s16x8*)(fb1_11 + kt * 32);
        s16x8 w12a = *(const s16x8*)(fb0_12 + kt * 32);
        s16x8 w12b = *(const s16x8*)(fb1_12 + kt * 32);
        mu0 = __builtin_amdgcn_mfma_f32_16x16x32_bf16(a, w11a, mu0, 0, 0, 0);
        mu1 = __builtin_amdgcn_mfma_f32_16x16x32_bf16(a, w11b, mu1, 0, 0, 0);
        lv0 = __builtin_amdgcn_mfma_f32_16x16x32_bf16(a, w12a, lv0, 0, 0, 0);
        lv1 = __builtin_amdgcn_mfma_f32_16x16x32_bf16(a, w12b, lv1, 0, 0, 0);
    }

    float b11_0 = fc11_b[j0], b11_1 = fc11_b[j1];
    float b12_0 = fc12_b[j0], b12_1 = fc12_b[j1];

    float kacc = 0.f;
#pragma unroll
    for (int r = 0; r < 4; ++r) {
        const int s = g * 4 + r;
        const int i = i0 + s;
        float m0 = mu0[r] + b11_0, m1 = mu1[r] + b11_1;
        float v0 = lv0[r] + b12_0, v1 = lv1[r] + b12_1;
        float e0 = eps[(size_t)i * DIM + j0];
        float e1 = eps[(size_t)i * DIM + j1];
        float z0 = e0 * expf(0.5f * v0) + m0;
        float z1 = e1 * expf(0.5f * v1) + m1;
        zbuf[(size_t)i * DIM + j0] = f2bf(z0);
        zbuf[(size_t)i * DIM + j1] = f2bf(z1);
        kacc += (1.f + v0 - m0 * m0 - expf(v0)) + (1.f + v1 - m1 * m1 - expf(v1));

        const size_t pb = (size_t)spi[s] * DIM;
        const size_t cb = (size_t)sci[s] * DIM;
        float pe0 = emb_item[pb + j0], pe1 = emb_item[pb + j1];
        float ce0 = emb_item[cb + j0], ce1 = emb_item[cb + j1];
        float zp = z0 * pe0 + z1 * pe1;
        float zc = z0 * ce0 + z1 * ce1;
        float d0 = z0 - pe0, d1 = z1 - pe1;
        float zq = d0 * d0 + d1 * d1;
        for (int m = 8; m >= 1; m >>= 1) {
            zp += __shfl_xor(zp, m, 64);
            zc += __shfl_xor(zc, m, 64);
            zq += __shfl_xor(zq, m, 64);
        }
        if (q == 0) {
            sdots[w][s][0] = zp;
            sdots[w][s][1] = zc;
            sdots[w][s][2] = zq;
        }
    }

    red[t] = -0.5f * kacc;
    __syncthreads();

    if (t < 16) {
        float zp = 0.f, zc = 0.f, zq = 0.f;
        for (int ww = 0; ww < 4; ++ww) {
            zp += sdots[ww][t][0];
            zc += sdots[ww][t][1];
            zq += sdots[ww][t][2];
        }
        float x = zp - zc;
        float ls = (x >= 0.f) ? -log1pf(expf(-x)) : (x - log1pf(expf(x)));
        red[t] += -ls + zq;
    }
    __syncthreads();
    for (int off = 128; off > 0; off >>= 1) {
        if (t < off) red[t] += red[t + off];
        __syncthreads();
    }
    if (t == 0) k2part[blockIdx.x] = red[0];
}

// ---------------------------------------------------------------------------
// K3: MFMA decoder -> mse partial. (unchanged)
// ---------------------------------------------------------------------------
__global__ __launch_bounds__(256) void k3_mfma(
    const int* __restrict__ pos_feat,
    const float* __restrict__ ef_item, const float* __restrict__ dec_b,
    const short* __restrict__ decWT, const short* __restrict__ zbuf,
    float* __restrict__ k3part)
{
    __shared__ int   featsL[16 * LI];
    __shared__ float red[256];

    const int t    = threadIdx.x;
    const int i0   = blockIdx.x * 16;
    const int w    = t >> 6;
    const int lane = t & 63;
    const int g    = lane >> 4;
    const int q    = lane & 15;

    if (t < 256) featsL[t] = pos_feat[i0 * LI + t];
    if (t < 64)  featsL[256 + t] = pos_feat[i0 * LI + 256 + t];
    __syncthreads();

    s16x8 za[4];
#pragma unroll
    for (int kt = 0; kt < 4; ++kt)
        za[kt] = *(const s16x8*)(zbuf + (size_t)(i0 + q) * DIM + kt * 32 + g * 8);

    float macc = 0.f;
    for (int fr = 0; fr < 40; ++fr) {
        const int c = w * 640 + fr * 16 + q;
        const short* bb = decWT + (size_t)c * DIM + g * 8;
        f32x4 acc = {0.f, 0.f, 0.f, 0.f};
#pragma unroll
        for (int kt = 0; kt < 4; ++kt) {
            s16x8 b = *(const s16x8*)(bb + kt * 32);
            acc = __builtin_amdgcn_mfma_f32_16x16x32_bf16(za[kt], b, acc, 0, 0, 0);
        }
        const float bias = dec_b[c];
        const int l = c >> 7, d = c & 127;
#pragma unroll
        for (int r = 0; r < 4; ++r) {
            const int s = g * 4 + r;
            const int f = featsL[s * LI + l];
            float x = ef_item[(size_t)f * DIM + d];
            float diff = acc[r] + bias - x;
            macc += diff * diff;
        }
    }

    red[t] = macc;
    __syncthreads();
    for (int off = 128; off > 0; off >>= 1) {
        if (t < off) red[t] += red[t + off];
        __syncthreads();
    }
    if (t == 0) k3part[blockIdx.x] = red[0];
}

// ---------------------------------------------------------------------------
// K4: final reduction -> item_vae_loss scalar.
// ---------------------------------------------------------------------------
__global__ __launch_bounds__(256) void k4_final(
    const float* __restrict__ k2part, const float* __restrict__ k3part,
    float* __restrict__ out_scalar)
{
    __shared__ float red[256];
    const int t = threadIdx.x;
    red[t] = k2part[t] + 0.05f * k3part[t];   // mse / LI  (LI = 20)
    __syncthreads();
    for (int off = 128; off > 0; off >>= 1) {
        if (t < off) red[t] += red[t + off];
        __syncthreads();
    }
    if (t == 0) out_scalar[0] = red[0];
}

// ---------------------------------------------------------------------------
extern "C" void kernel_launch(void* const* d_in, const int* in_sizes, int n_in,
                              void* d_out, int out_size, void* d_ws, size_t ws_size,
                              hipStream_t stream) {
    const int*   user_idx  = (const int*)d_in[0];
    const int*   user_feat = (const int*)d_in[1];
    const int*   pos_idx   = (const int*)d_in[2];
    const int*   pos_feat  = (const int*)d_in[3];
    const int*   neg_idx   = (const int*)d_in[4];
    const int*   neg_feat  = (const int*)d_in[5];
    const int*   comp_idx  = (const int*)d_in[6];
    const float* eps       = (const float*)d_in[7];
    const float* emb_user  = (const float*)d_in[8];
    const float* emb_item  = (const float*)d_in[9];
    const float* ef_user   = (const float*)d_in[10];
    const float* ef_item   = (const float*)d_in[11];
    const float* pop_u     = (const float*)d_in[12];
    const float* int_u     = (const float*)d_in[13];
    const float* pop_i     = (const float*)d_in[14];
    const float* int_i     = (const float*)d_in[15];
    const float* W_pop     = (const float*)d_in[16];
    const float* W_int     = (const float*)d_in[18];
    const float* enc_W     = (const float*)d_in[20];
    const float* enc_b     = (const float*)d_in[21];
    const float* dec_W     = (const float*)d_in[22];
    const float* dec_b     = (const float*)d_in[23];
    const float* fc11_W    = (const float*)d_in[24];
    const float* fc11_b    = (const float*)d_in[25];
    const float* fc12_W    = (const float*)d_in[26];
    const float* fc12_b    = (const float*)d_in[27];

    float* out = (float*)d_out;
    char*  ws  = (char*)d_ws;

    short* zbuf   = (short*)(ws);                  // 1,048,576 B
    short* encWT  = (short*)(ws + 1048576);        //   655,360
    short* decWT  = (short*)(ws + 1703936);        //   655,360
    short* fc11WT = (short*)(ws + 2359296);        //    32,768
    short* fc12WT = (short*)(ws + 2392064);        //    32,768
    short* wpopT  = (short*)(ws + 2424832);        //    32,768
    short* wintT  = (short*)(ws + 2457600);        //    32,768
    short* ef16   = (short*)(ws + 2490368);        // 1,280,000
    float* pooled = (float*)(ws + 3770368);        // 6*4096*128*4 = 12,582,912
    float* k2part = (float*)(ws + 16353280);       // 1,024
    float* k3part = (float*)(ws + 16354304);       // 1,024

    const size_t SEC = (size_t)BATCH * DIM;        // one pooled section

    k0_prep<<<dim3(1329), dim3(256), 0, stream>>>(
        enc_W, dec_W, fc11_W, fc12_W, W_pop, W_int, ef_item,
        encWT, decWT, fc11WT, fc12WT, wpopT, wintT, ef16);

    k1a_pool<LU><<<dim3(512), dim3(256), 0, stream>>>(
        user_idx, user_feat, emb_user, ef_user, pop_u, int_u,
        pooled + 0 * SEC, pooled + 1 * SEC);
    k1a_pool<LI><<<dim3(512), dim3(256), 0, stream>>>(
        pos_idx, pos_feat, emb_item, ef_item, pop_i, int_i,
        pooled + 2 * SEC, pooled + 3 * SEC);
    k1a_pool<LI><<<dim3(512), dim3(256), 0, stream>>>(
        neg_idx, neg_feat, emb_item, ef_item, pop_i, int_i,
        pooled + 4 * SEC, pooled + 5 * SEC);

    k2_mfma<<<dim3(BATCH / 16), dim3(256), 0, stream>>>(
        pos_feat, pos_idx, comp_idx, emb_item, eps,
        enc_b, fc11_b, fc12_b, encWT, fc11WT, fc12WT, ef16,
        zbuf, k2part);

    k3_mfma<<<dim3(BATCH / 16), dim3(256), 0, stream>>>(
        pos_feat, ef_item, dec_b, decWT, zbuf, k3part);

    k1b_loss<<<dim3(BATCH / 16), dim3(256), 0, stream>>>(
        pooled, wpopT, wintT, out, out + BATCH);

    k4_final<<<dim3(1), dim3(256), 0, stream>>>(k2part, k3part, out + 2 * BATCH);
}

// Round 4
// 98.424 us; speedup vs baseline: 7.1292x; 1.5149x over previous
//
#include <hip/hip_runtime.h>
#include <math.h>

#define BATCH 4096
#define DIM 128
#define LU 10
#define LI 20

typedef float  f32x4  __attribute__((ext_vector_type(4)));
typedef short  s16x8  __attribute__((ext_vector_type(8)));

// round-to-nearest-even fp32 -> bf16
__device__ __forceinline__ short f2bf(float x) {
    unsigned u = __float_as_uint(x);
    u += 0x7FFFu + ((u >> 16) & 1u);
    return (short)(u >> 16);
}

// ---------------------------------------------------------------------------
// K0: prep — transpose+convert weights to bf16, convert ef_item to bf16.
// ---------------------------------------------------------------------------
__global__ __launch_bounds__(256) void k0_prep(
    const float* __restrict__ enc_W, const float* __restrict__ dec_W,
    const float* __restrict__ fc11_W, const float* __restrict__ fc12_W,
    const float* __restrict__ W_pop, const float* __restrict__ W_int,
    const float* __restrict__ ef_item,
    short* __restrict__ encWT, short* __restrict__ decWT,
    short* __restrict__ fc11WT, short* __restrict__ fc12WT,
    short* __restrict__ wpopT, short* __restrict__ wintT,
    short* __restrict__ ef16)
{
    __shared__ float tile[32][33];
    const int b = blockIdx.x;
    const int t = threadIdx.x;

    if (b < 704) {
        const float* src; short* dst; int r0, c0, src_ld, dst_ld;
        if (b < 320) {           // enc_W [2560][128] -> encWT [128][2560]
            int tk = b % 80, tj = b / 80;
            src = enc_W; dst = encWT; r0 = tk * 32; c0 = tj * 32; src_ld = 128; dst_ld = 2560;
        } else if (b < 640) {    // dec_W [128][2560] -> decWT [2560][128]
            int tb = b - 320; int tc = tb % 80, td = tb / 80;
            src = dec_W; dst = decWT; r0 = td * 32; c0 = tc * 32; src_ld = 2560; dst_ld = 128;
        } else if (b < 656) {
            int tb = b - 640; int tk = tb % 4, tj = tb / 4;
            src = fc11_W; dst = fc11WT; r0 = tk * 32; c0 = tj * 32; src_ld = 128; dst_ld = 128;
        } else if (b < 672) {
            int tb = b - 656; int tk = tb % 4, tj = tb / 4;
            src = fc12_W; dst = fc12WT; r0 = tk * 32; c0 = tj * 32; src_ld = 128; dst_ld = 128;
        } else if (b < 688) {
            int tb = b - 672; int tk = tb % 4, tj = tb / 4;
            src = W_pop; dst = wpopT; r0 = tk * 32; c0 = tj * 32; src_ld = 128; dst_ld = 128;
        } else {
            int tb = b - 688; int tk = tb % 4, tj = tb / 4;
            src = W_int; dst = wintT; r0 = tk * 32; c0 = tj * 32; src_ld = 128; dst_ld = 128;
        }
        for (int q = 0; q < 4; ++q) {
            int e = t + q * 256;
            int r = e >> 5, c = e & 31;
            tile[r][c] = src[(size_t)(r0 + r) * src_ld + (c0 + c)];
        }
        __syncthreads();
        for (int q = 0; q < 4; ++q) {
            int e = t + q * 256;
            int r = e >> 5, c = e & 31;
            dst[(size_t)(c0 + r) * dst_ld + (r0 + c)] = f2bf(tile[c][r]);
        }
    } else {
        int base = (b - 704) * 1024 + t * 4;
        float4 v = *(const float4*)(ef_item + base);
        short4 o;
        o.x = f2bf(v.x); o.y = f2bf(v.y); o.z = f2bf(v.z); o.w = f2bf(v.w);
        *(short4*)(ef16 + base) = o;
    }
}

// ---------------------------------------------------------------------------
// K1a: attention pooling, barrier-free, all three branches in one launch.
// Each 32-lane half-wave handles one sample; lane owns 4 dims (float4).
// ---------------------------------------------------------------------------
template<int L>
__device__ __forceinline__ void pool_one(
    const int* __restrict__ idxp, const int* __restrict__ featp,
    const float* __restrict__ etab, const float* __restrict__ ftab,
    const float* __restrict__ vpop, const float* __restrict__ vint,
    float* __restrict__ poolH, float* __restrict__ poolC,
    int i, int j32)
{
    const int d = j32 * 4;
    const float4 vp = *(const float4*)(vpop + d);
    const float4 vi = *(const float4*)(vint + d);

    const int idx = idxp[i];
    const float4 f0 = *(const float4*)(etab + (size_t)idx * DIM + d);

    float sp[L + 1], si[L + 1];
    sp[0] = f0.x * vp.x + f0.y * vp.y + f0.z * vp.z + f0.w * vp.w;
    si[0] = f0.x * vi.x + f0.y * vi.y + f0.z * vi.z + f0.w * vi.w;

    unsigned mbits = 1u;
    int fidx[L];
#pragma unroll
    for (int l = 0; l < L; ++l) {
        int f = featp[i * L + l];
        fidx[l] = f;
        mbits |= (f != 0 ? 2u : 0u) << l;
        float4 fv = *(const float4*)(ftab + (size_t)f * DIM + d);
        sp[l + 1] = fv.x * vp.x + fv.y * vp.y + fv.z * vp.z + fv.w * vp.w;
        si[l + 1] = fv.x * vi.x + fv.y * vi.y + fv.z * vi.z + fv.w * vi.w;
    }

#pragma unroll
    for (int l = 0; l <= L; ++l) {
        float a = sp[l], b = si[l];
        for (int m = 16; m >= 1; m >>= 1) {
            a += __shfl_xor(a, m, 64);
            b += __shfl_xor(b, m, 64);
        }
        sp[l] = a; si[l] = b;
    }

    float mh = sp[0], mc = si[0];
#pragma unroll
    for (int l = 1; l <= L; ++l) {
        bool v = (mbits >> l) & 1u;
        mh = v ? fmaxf(mh, sp[l]) : mh;
        mc = v ? fmaxf(mc, si[l]) : mc;
    }
    float sh = 0.f, sc = 0.f;
#pragma unroll
    for (int l = 0; l <= L; ++l) {
        bool v = (mbits >> l) & 1u;
        float eh = v ? __expf(sp[l] - mh) : 0.f;
        float ec = v ? __expf(si[l] - mc) : 0.f;
        sp[l] = eh; si[l] = ec;
        sh += eh; sc += ec;
    }
    const float rh = 1.f / sh, rc = 1.f / sc;

    float phx = sp[0] * f0.x, phy = sp[0] * f0.y, phz = sp[0] * f0.z, phw = sp[0] * f0.w;
    float pcx = si[0] * f0.x, pcy = si[0] * f0.y, pcz = si[0] * f0.z, pcw = si[0] * f0.w;
#pragma unroll
    for (int l = 0; l < L; ++l) {
        float4 fv = *(const float4*)(ftab + (size_t)fidx[l] * DIM + d);
        float wh = sp[l + 1], wc = si[l + 1];
        phx += wh * fv.x; phy += wh * fv.y; phz += wh * fv.z; phw += wh * fv.w;
        pcx += wc * fv.x; pcy += wc * fv.y; pcz += wc * fv.z; pcw += wc * fv.w;
    }
    float4 rH; rH.x = phx * rh; rH.y = phy * rh; rH.z = phz * rh; rH.w = phw * rh;
    float4 rC; rC.x = pcx * rc; rC.y = pcy * rc; rC.z = pcz * rc; rC.w = pcw * rc;
    *(float4*)(poolH + (size_t)i * DIM + d) = rH;
    *(float4*)(poolC + (size_t)i * DIM + d) = rC;
}

__global__ __launch_bounds__(256) void k1a_all(
    const int* __restrict__ user_idx, const int* __restrict__ user_feat,
    const int* __restrict__ pos_idx,  const int* __restrict__ pos_feat,
    const int* __restrict__ neg_idx,  const int* __restrict__ neg_feat,
    const float* __restrict__ emb_user, const float* __restrict__ emb_item,
    const float* __restrict__ ef_user,  const float* __restrict__ ef_item,
    const float* __restrict__ pop_u, const float* __restrict__ int_u,
    const float* __restrict__ pop_i, const float* __restrict__ int_i,
    float* __restrict__ pooled)
{
    const int b   = blockIdx.x;
    const int t   = threadIdx.x;
    const int w   = t >> 6;
    const int lid = t & 63;
    const int h2  = lid >> 5;
    const int j32 = lid & 31;
    const size_t SEC = (size_t)BATCH * DIM;

    if (b < 512) {
        const int i = (b * 4 + w) * 2 + h2;
        pool_one<LU>(user_idx, user_feat, emb_user, ef_user, pop_u, int_u,
                     pooled + 0 * SEC, pooled + 1 * SEC, i, j32);
    } else if (b < 1024) {
        const int i = ((b - 512) * 4 + w) * 2 + h2;
        pool_one<LI>(pos_idx, pos_feat, emb_item, ef_item, pop_i, int_i,
                     pooled + 2 * SEC, pooled + 3 * SEC, i, j32);
    } else {
        const int i = ((b - 1024) * 4 + w) * 2 + h2;
        pool_one<LI>(neg_idx, neg_feat, emb_item, ef_item, pop_i, int_i,
                     pooled + 4 * SEC, pooled + 5 * SEC, i, j32);
    }
}

// ---------------------------------------------------------------------------
// K1b: triplet losses via MFMA (biases cancel in differences).
// ---------------------------------------------------------------------------
__global__ __launch_bounds__(256) void k1b_loss(
    const float* __restrict__ pooled, const short* __restrict__ wpopT,
    const short* __restrict__ wintT,
    float* __restrict__ out_hot, float* __restrict__ out_cold)
{
    __shared__ float sArr[4][16];
    const int t    = threadIdx.x;
    const int w    = t >> 6;
    const int lane = t & 63;
    const int g    = lane >> 4;
    const int q    = lane & 15;
    const int i0   = blockIdx.x * 16;

    const int h     = w >> 1;
    const int other = (w & 1) + 1;
    const float* pu = pooled + (size_t)(0 * 2 + h) * BATCH * DIM;
    const float* po = pooled + (size_t)(other * 2 + h) * BATCH * DIM;
    const short* wT = h ? wintT : wpopT;

    s16x8 afr[4];
#pragma unroll
    for (int kt = 0; kt < 4; ++kt) {
        const size_t off = (size_t)(i0 + q) * DIM + kt * 32 + g * 8;
        f32x4 ua = *(const f32x4*)(pu + off);
        f32x4 ub = *(const f32x4*)(pu + off + 4);
        f32x4 oa = *(const f32x4*)(po + off);
        f32x4 ob = *(const f32x4*)(po + off + 4);
        s16x8 v;
        v[0] = f2bf(ua[0] - oa[0]); v[1] = f2bf(ua[1] - oa[1]);
        v[2] = f2bf(ua[2] - oa[2]); v[3] = f2bf(ua[3] - oa[3]);
        v[4] = f2bf(ub[0] - ob[0]); v[5] = f2bf(ub[1] - ob[1]);
        v[6] = f2bf(ub[2] - ob[2]); v[7] = f2bf(ub[3] - ob[3]);
        afr[kt] = v;
    }

    float sq0 = 0.f, sq1 = 0.f, sq2 = 0.f, sq3 = 0.f;
    for (int fr = 0; fr < 8; ++fr) {
        const short* bb = wT + (size_t)(fr * 16 + q) * DIM + g * 8;
        f32x4 acc = {0.f, 0.f, 0.f, 0.f};
#pragma unroll
        for (int kt = 0; kt < 4; ++kt) {
            s16x8 bfr = *(const s16x8*)(bb + kt * 32);
            acc = __builtin_amdgcn_mfma_f32_16x16x32_bf16(afr[kt], bfr, acc, 0, 0, 0);
        }
        sq0 += acc[0] * acc[0]; sq1 += acc[1] * acc[1];
        sq2 += acc[2] * acc[2]; sq3 += acc[3] * acc[3];
    }
    for (int m = 8; m >= 1; m >>= 1) {
        sq0 += __shfl_xor(sq0, m, 64);
        sq1 += __shfl_xor(sq1, m, 64);
        sq2 += __shfl_xor(sq2, m, 64);
        sq3 += __shfl_xor(sq3, m, 64);
    }
    if (q == 0) {
        sArr[w][g * 4 + 0] = sq0;
        sArr[w][g * 4 + 1] = sq1;
        sArr[w][g * 4 + 2] = sq2;
        sArr[w][g * 4 + 3] = sq3;
    }
    __syncthreads();
    if (t < 16) {
        float v = sArr[0][t] - sArr[1][t] + 1.0f;
        out_hot[i0 + t] = v > 0.f ? v : 0.f;
    } else if (t < 32) {
        int s = t - 16;
        float v = sArr[2][s] - sArr[3][s] + 1.0f;
        out_cold[i0 + s] = v > 0.f ? v : 0.f;
    }
}

// ---------------------------------------------------------------------------
// K2: MFMA encoder + mu/lv + z + kld/mmi/zsq partials. (unchanged)
// ---------------------------------------------------------------------------
__global__ __launch_bounds__(256) void k2_mfma(
    const int* __restrict__ pos_feat, const int* __restrict__ pos_idx,
    const int* __restrict__ comp_idx,
    const float* __restrict__ emb_item, const float* __restrict__ eps,
    const float* __restrict__ enc_b,
    const float* __restrict__ fc11_b, const float* __restrict__ fc12_b,
    const short* __restrict__ encWT, const short* __restrict__ fc11WT,
    const short* __restrict__ fc12WT, const short* __restrict__ ef16,
    short* __restrict__ zbuf, float* __restrict__ k2part)
{
    __shared__ int   featsL[16 * LI];
    __shared__ int   spi[16], sci[16];
    __shared__ __align__(16) short hlds[16 * 128];
    __shared__ float sdots[4][16][3];
    __shared__ float red[256];

    const int t    = threadIdx.x;
    const int i0   = blockIdx.x * 16;
    const int w    = t >> 6;
    const int lane = t & 63;
    const int g    = lane >> 4;
    const int q    = lane & 15;

    if (t < 16)      spi[t] = pos_idx[i0 + t];
    else if (t < 32) sci[t - 16] = comp_idx[i0 + t - 16];
    if (t < 256) featsL[t] = pos_feat[i0 * LI + t];
    if (t < 64)  featsL[256 + t] = pos_feat[i0 * LI + 256 + t];
    __syncthreads();

    const int j0 = w * 32 + q;
    const int j1 = j0 + 16;
    const short* bbase0 = encWT + (size_t)j0 * 2560 + g * 8;
    const short* bbase1 = encWT + (size_t)j1 * 2560 + g * 8;

    f32x4 acc0 = {0.f, 0.f, 0.f, 0.f};
    f32x4 acc1 = {0.f, 0.f, 0.f, 0.f};

    for (int l = 0; l < LI; ++l) {
        const int f = featsL[q * LI + l];
        const short* arow = ef16 + (size_t)f * DIM + g * 8;
#pragma unroll
        for (int dt = 0; dt < 4; ++dt) {
            const int koff = l * 128 + dt * 32;
            s16x8 a  = *(const s16x8*)(arow + dt * 32);
            s16x8 b0 = *(const s16x8*)(bbase0 + koff);
            s16x8 b1 = *(const s16x8*)(bbase1 + koff);
            acc0 = __builtin_amdgcn_mfma_f32_16x16x32_bf16(a, b0, acc0, 0, 0, 0);
            acc1 = __builtin_amdgcn_mfma_f32_16x16x32_bf16(a, b1, acc1, 0, 0, 0);
        }
    }

    {
        float eb0 = enc_b[j0], eb1 = enc_b[j1];
#pragma unroll
        for (int r = 0; r < 4; ++r) {
            int s = g * 4 + r;
            float h0 = acc0[r] + eb0; h0 = h0 > 0.f ? h0 : 0.f;
            float h1 = acc1[r] + eb1; h1 = h1 > 0.f ? h1 : 0.f;
            int swz = (s & 7) << 3;
            hlds[(s * 128 + j0) ^ swz] = f2bf(h0);
            hlds[(s * 128 + j1) ^ swz] = f2bf(h1);
        }
    }
    __syncthreads();

    const short* fb0_11 = fc11WT + (size_t)j0 * DIM + g * 8;
    const short* fb1_11 = fc11WT + (size_t)j1 * DIM + g * 8;
    const short* fb0_12 = fc12WT + (size_t)j0 * DIM + g * 8;
    const short* fb1_12 = fc12WT + (size_t)j1 * DIM + g * 8;

    f32x4 mu0 = {0.f,0.f,0.f,0.f}, mu1 = {0.f,0.f,0.f,0.f};
    f32x4 lv0 = {0.f,0.f,0.f,0.f}, lv1 = {0.f,0.f,0.f,0.f};
#pragma unroll
    for (int kt = 0; kt < 4; ++kt) {
        int sidx = (q * 128 + kt * 32 + g * 8) ^ ((q & 7) << 3);
        s16x8 a = *(const s16x8*)&hlds[sidx];
        s16x8 w11a = *(const s16x8*)(fb0_11 + kt * 32);
        s16x8 w11b = *(const s16x8*)(fb1_11 + kt * 32);
        s16x8 w12a = *(const s16x8*)(fb0_12 + kt * 32);
        s16x8 w12b = *(const s16x8*)(fb1_12 + kt * 32);
        mu0 = __builtin_amdgcn_mfma_f32_16x16x32_bf16(a, w11a, mu0, 0, 0, 0);
        mu1 = __builtin_amdgcn_mfma_f32_16x16x32_bf16(a, w11b, mu1, 0, 0, 0);
        lv0 = __builtin_amdgcn_mfma_f32_16x16x32_bf16(a, w12a, lv0, 0, 0, 0);
        lv1 = __builtin_amdgcn_mfma_f32_16x16x32_bf16(a, w12b, lv1, 0, 0, 0);
    }

    float b11_0 = fc11_b[j0], b11_1 = fc11_b[j1];
    float b12_0 = fc12_b[j0], b12_1 = fc12_b[j1];

    float kacc = 0.f;
#pragma unroll
    for (int r = 0; r < 4; ++r) {
        const int s = g * 4 + r;
        const int i = i0 + s;
        float m0 = mu0[r] + b11_0, m1 = mu1[r] + b11_1;
        float v0 = lv0[r] + b12_0, v1 = lv1[r] + b12_1;
        float e0 = eps[(size_t)i * DIM + j0];
        float e1 = eps[(size_t)i * DIM + j1];
        float z0 = e0 * expf(0.5f * v0) + m0;
        float z1 = e1 * expf(0.5f * v1) + m1;
        zbuf[(size_t)i * DIM + j0] = f2bf(z0);
        zbuf[(size_t)i * DIM + j1] = f2bf(z1);
        kacc += (1.f + v0 - m0 * m0 - expf(v0)) + (1.f + v1 - m1 * m1 - expf(v1));

        const size_t pb = (size_t)spi[s] * DIM;
        const size_t cb = (size_t)sci[s] * DIM;
        float pe0 = emb_item[pb + j0], pe1 = emb_item[pb + j1];
        float ce0 = emb_item[cb + j0], ce1 = emb_item[cb + j1];
        float zp = z0 * pe0 + z1 * pe1;
        float zc = z0 * ce0 + z1 * ce1;
        float d0 = z0 - pe0, d1 = z1 - pe1;
        float zq = d0 * d0 + d1 * d1;
        for (int m = 8; m >= 1; m >>= 1) {
            zp += __shfl_xor(zp, m, 64);
            zc += __shfl_xor(zc, m, 64);
            zq += __shfl_xor(zq, m, 64);
        }
        if (q == 0) {
            sdots[w][s][0] = zp;
            sdots[w][s][1] = zc;
            sdots[w][s][2] = zq;
        }
    }

    red[t] = -0.5f * kacc;
    __syncthreads();

    if (t < 16) {
        float zp = 0.f, zc = 0.f, zq = 0.f;
        for (int ww = 0; ww < 4; ++ww) {
            zp += sdots[ww][t][0];
            zc += sdots[ww][t][1];
            zq += sdots[ww][t][2];
        }
        float x = zp - zc;
        float ls = (x >= 0.f) ? -log1pf(expf(-x)) : (x - log1pf(expf(x)));
        red[t] += -ls + zq;
    }
    __syncthreads();
    for (int off = 128; off > 0; off >>= 1) {
        if (t < off) red[t] += red[t + off];
        __syncthreads();
    }
    if (t == 0) k2part[blockIdx.x] = red[0];
}

// ---------------------------------------------------------------------------
// K3: MFMA decoder -> mse partial. 4-way column split: 1024 blocks.
// Block = (cchunk = bid>>8, sample-block = bid&255). Each wave: 160 cols
// (10 frags), processed in 2-frag batches for memory-level parallelism.
// ---------------------------------------------------------------------------
__global__ __launch_bounds__(256) void k3_mfma(
    const int* __restrict__ pos_feat,
    const float* __restrict__ ef_item, const float* __restrict__ dec_b,
    const short* __restrict__ decWT, const short* __restrict__ zbuf,
    float* __restrict__ k3part)
{
    __shared__ int   featsL[16 * LI];
    __shared__ float red[256];

    const int t      = threadIdx.x;
    const int cchunk = blockIdx.x >> 8;
    const int sb     = blockIdx.x & 255;
    const int i0     = sb * 16;
    const int w      = t >> 6;
    const int lane   = t & 63;
    const int g      = lane >> 4;
    const int q      = lane & 15;

    if (t < 256) featsL[t] = pos_feat[i0 * LI + t];
    if (t < 64)  featsL[256 + t] = pos_feat[i0 * LI + 256 + t];
    __syncthreads();

    s16x8 za[4];
#pragma unroll
    for (int kt = 0; kt < 4; ++kt)
        za[kt] = *(const s16x8*)(zbuf + (size_t)(i0 + q) * DIM + kt * 32 + g * 8);

    const int cw = cchunk * 640 + w * 160;
    float macc = 0.f;

#pragma unroll
    for (int fp = 0; fp < 5; ++fp) {           // 2 frags per iteration
        const int c0 = cw + fp * 32 + q;
        const int c1 = c0 + 16;
        const short* bb0 = decWT + (size_t)c0 * DIM + g * 8;
        const short* bb1 = decWT + (size_t)c1 * DIM + g * 8;

        s16x8 b0[4], b1[4];
#pragma unroll
        for (int kt = 0; kt < 4; ++kt) {
            b0[kt] = *(const s16x8*)(bb0 + kt * 32);
            b1[kt] = *(const s16x8*)(bb1 + kt * 32);
        }

        const int l0 = c0 >> 7, d0 = c0 & 127;
        const int l1 = c1 >> 7, d1 = c1 & 127;
        float x0[4], x1[4];
#pragma unroll
        for (int r = 0; r < 4; ++r) {
            const int s = g * 4 + r;
            x0[r] = ef_item[(size_t)featsL[s * LI + l0] * DIM + d0];
            x1[r] = ef_item[(size_t)featsL[s * LI + l1] * DIM + d1];
        }
        const float bias0 = dec_b[c0];
        const float bias1 = dec_b[c1];

        f32x4 acc0 = {0.f, 0.f, 0.f, 0.f};
        f32x4 acc1 = {0.f, 0.f, 0.f, 0.f};
#pragma unroll
        for (int kt = 0; kt < 4; ++kt) {
            acc0 = __builtin_amdgcn_mfma_f32_16x16x32_bf16(za[kt], b0[kt], acc0, 0, 0, 0);
            acc1 = __builtin_amdgcn_mfma_f32_16x16x32_bf16(za[kt], b1[kt], acc1, 0, 0, 0);
        }
#pragma unroll
        for (int r = 0; r < 4; ++r) {
            float dd0 = acc0[r] + bias0 - x0[r];
            float dd1 = acc1[r] + bias1 - x1[r];
            macc += dd0 * dd0 + dd1 * dd1;
        }
    }

    red[t] = macc;
    __syncthreads();
    for (int off = 128; off > 0; off >>= 1) {
        if (t < off) red[t] += red[t + off];
        __syncthreads();
    }
    if (t == 0) k3part[blockIdx.x] = red[0];
}

// ---------------------------------------------------------------------------
// K4: final reduction -> item_vae_loss scalar. (k3part now 1024 entries)
// ---------------------------------------------------------------------------
__global__ __launch_bounds__(256) void k4_final(
    const float* __restrict__ k2part, const float* __restrict__ k3part,
    float* __restrict__ out_scalar)
{
    __shared__ float red[256];
    const int t = threadIdx.x;
    float b3 = 0.f;
    for (int qq = t; qq < 1024; qq += 256) b3 += k3part[qq];
    red[t] = k2part[t] + 0.05f * b3;   // mse / LI  (LI = 20)
    __syncthreads();
    for (int off = 128; off > 0; off >>= 1) {
        if (t < off) red[t] += red[t + off];
        __syncthreads();
    }
    if (t == 0) out_scalar[0] = red[0];
}

// ---------------------------------------------------------------------------
extern "C" void kernel_launch(void* const* d_in, const int* in_sizes, int n_in,
                              void* d_out, int out_size, void* d_ws, size_t ws_size,
                              hipStream_t stream) {
    const int*   user_idx  = (const int*)d_in[0];
    const int*   user_feat = (const int*)d_in[1];
    const int*   pos_idx   = (const int*)d_in[2];
    const int*   pos_feat  = (const int*)d_in[3];
    const int*   neg_idx   = (const int*)d_in[4];
    const int*   neg_feat  = (const int*)d_in[5];
    const int*   comp_idx  = (const int*)d_in[6];
    const float* eps       = (const float*)d_in[7];
    const float* emb_user  = (const float*)d_in[8];
    const float* emb_item  = (const float*)d_in[9];
    const float* ef_user   = (const float*)d_in[10];
    const float* ef_item   = (const float*)d_in[11];
    const float* pop_u     = (const float*)d_in[12];
    const float* int_u     = (const float*)d_in[13];
    const float* pop_i     = (const float*)d_in[14];
    const float* int_i     = (const float*)d_in[15];
    const float* W_pop     = (const float*)d_in[16];
    const float* W_int     = (const float*)d_in[18];
    const float* enc_W     = (const float*)d_in[20];
    const float* enc_b     = (const float*)d_in[21];
    const float* dec_W     = (const float*)d_in[22];
    const float* dec_b     = (const float*)d_in[23];
    const float* fc11_W    = (const float*)d_in[24];
    const float* fc11_b    = (const float*)d_in[25];
    const float* fc12_W    = (const float*)d_in[26];
    const float* fc12_b    = (const float*)d_in[27];

    float* out = (float*)d_out;
    char*  ws  = (char*)d_ws;

    short* zbuf   = (short*)(ws);                  // 1,048,576 B
    short* encWT  = (short*)(ws + 1048576);        //   655,360
    short* decWT  = (short*)(ws + 1703936);        //   655,360
    short* fc11WT = (short*)(ws + 2359296);        //    32,768
    short* fc12WT = (short*)(ws + 2392064);        //    32,768
    short* wpopT  = (short*)(ws + 2424832);        //    32,768
    short* wintT  = (short*)(ws + 2457600);        //    32,768
    short* ef16   = (short*)(ws + 2490368);        // 1,280,000
    float* pooled = (float*)(ws + 3770368);        // 12,582,912
    float* k2part = (float*)(ws + 16353280);       // 1,024
    float* k3part = (float*)(ws + 16354304);       // 4,096

    k0_prep<<<dim3(1329), dim3(256), 0, stream>>>(
        enc_W, dec_W, fc11_W, fc12_W, W_pop, W_int, ef_item,
        encWT, decWT, fc11WT, fc12WT, wpopT, wintT, ef16);

    k1a_all<<<dim3(1536), dim3(256), 0, stream>>>(
        user_idx, user_feat, pos_idx, pos_feat, neg_idx, neg_feat,
        emb_user, emb_item, ef_user, ef_item,
        pop_u, int_u, pop_i, int_i, pooled);

    k2_mfma<<<dim3(BATCH / 16), dim3(256), 0, stream>>>(
        pos_feat, pos_idx, comp_idx, emb_item, eps,
        enc_b, fc11_b, fc12_b, encWT, fc11WT, fc12WT, ef16,
        zbuf, k2part);

    k3_mfma<<<dim3(1024), dim3(256), 0, stream>>>(
        pos_feat, ef_item, dec_b, decWT, zbuf, k3part);

    k1b_loss<<<dim3(BATCH / 16), dim3(256), 0, stream>>>(
        pooled, wpopT, wintT, out, out + BATCH);

    k4_final<<<dim3(1), dim3(256), 0, stream>>>(k2part, k3part, out + 2 * BATCH);
}

// Round 5
// 93.924 us; speedup vs baseline: 7.4708x; 1.0479x over previous
//
#include <hip/hip_runtime.h>
#include <math.h>

#define BATCH 4096
#define DIM 128
#define LU 10
#define LI 20

typedef float  f32x4  __attribute__((ext_vector_type(4)));
typedef short  s16x8  __attribute__((ext_vector_type(8)));

// round-to-nearest-even fp32 -> bf16
__device__ __forceinline__ short f2bf(float x) {
    unsigned u = __float_as_uint(x);
    u += 0x7FFFu + ((u >> 16) & 1u);
    return (short)(u >> 16);
}

// ---------------------------------------------------------------------------
// k1a pooling: ONE WAVE per (sample, branch). Lanes 0-31 handle the pop/hot
// vector, lanes 32-63 the int/cold vector. 5-round butterfly stays within
// each 32-lane half. Row loads identical across halves (cache-merged).
// ---------------------------------------------------------------------------
template<int L>
__device__ __forceinline__ void pool_wave(
    const int* __restrict__ idxp, const int* __restrict__ featp,
    const float* __restrict__ etab, const float* __restrict__ ftab,
    const float* __restrict__ vpop, const float* __restrict__ vint,
    float* __restrict__ poolH, float* __restrict__ poolC,
    int i, int lane)
{
    const int h   = lane >> 5;
    const int j32 = lane & 31;
    const int d   = j32 * 4;
    const float* vecp = h ? vint : vpop;
    const float4 vv = *(const float4*)(vecp + d);

    const int idx = idxp[i];
    const float4 f0 = *(const float4*)(etab + (size_t)idx * DIM + d);

    float s[L + 1];
    int fidx[L];
    s[0] = f0.x * vv.x + f0.y * vv.y + f0.z * vv.z + f0.w * vv.w;
    unsigned mbits = 1u;
#pragma unroll
    for (int l = 0; l < L; ++l) {
        int f = featp[i * L + l];
        fidx[l] = f;
        mbits |= (f != 0 ? 2u : 0u) << l;
        float4 fv = *(const float4*)(ftab + (size_t)f * DIM + d);
        s[l + 1] = fv.x * vv.x + fv.y * vv.y + fv.z * vv.z + fv.w * vv.w;
    }

#pragma unroll
    for (int l = 0; l <= L; ++l) {
        float a = s[l];
        a += __shfl_xor(a, 1, 64);
        a += __shfl_xor(a, 2, 64);
        a += __shfl_xor(a, 4, 64);
        a += __shfl_xor(a, 8, 64);
        a += __shfl_xor(a, 16, 64);
        s[l] = a;
    }

    float mx = s[0];
#pragma unroll
    for (int l = 1; l <= L; ++l)
        mx = ((mbits >> l) & 1u) ? fmaxf(mx, s[l]) : mx;
    float ssum = 0.f;
#pragma unroll
    for (int l = 0; l <= L; ++l) {
        float e = ((mbits >> l) & 1u) ? __expf(s[l] - mx) : 0.f;
        s[l] = e; ssum += e;
    }
    const float rinv = 1.f / ssum;

    float ax = s[0] * f0.x, ay = s[0] * f0.y, az = s[0] * f0.z, aw = s[0] * f0.w;
#pragma unroll
    for (int l = 0; l < L; ++l) {
        float4 fv = *(const float4*)(ftab + (size_t)fidx[l] * DIM + d);
        float wl = s[l + 1];
        ax += wl * fv.x; ay += wl * fv.y; az += wl * fv.z; aw += wl * fv.w;
    }
    float4 o; o.x = ax * rinv; o.y = ay * rinv; o.z = az * rinv; o.w = aw * rinv;
    float* dst = h ? poolC : poolH;
    *(float4*)(dst + (size_t)i * DIM + d) = o;
}

// ---------------------------------------------------------------------------
// K01: merged pooling (blocks 0..3071) + weight prep (blocks 3072..4400).
// ---------------------------------------------------------------------------
__global__ __launch_bounds__(256) void k01_pool_prep(
    const int* __restrict__ user_idx, const int* __restrict__ user_feat,
    const int* __restrict__ pos_idx,  const int* __restrict__ pos_feat,
    const int* __restrict__ neg_idx,  const int* __restrict__ neg_feat,
    const float* __restrict__ emb_user, const float* __restrict__ emb_item,
    const float* __restrict__ ef_user,  const float* __restrict__ ef_item,
    const float* __restrict__ pop_u, const float* __restrict__ int_u,
    const float* __restrict__ pop_i, const float* __restrict__ int_i,
    const float* __restrict__ enc_W, const float* __restrict__ dec_W,
    const float* __restrict__ fc11_W, const float* __restrict__ fc12_W,
    const float* __restrict__ W_pop, const float* __restrict__ W_int,
    float* __restrict__ pooled,
    short* __restrict__ encWT, short* __restrict__ decWT,
    short* __restrict__ fc11WT, short* __restrict__ fc12WT,
    short* __restrict__ wpopT, short* __restrict__ wintT,
    short* __restrict__ ef16)
{
    __shared__ float tile[32][33];
    const int b = blockIdx.x;
    const int t = threadIdx.x;
    const size_t SEC = (size_t)BATCH * DIM;

    if (b < 3072) {
        const int w    = t >> 6;
        const int lane = t & 63;
        if (b < 1024) {
            const int i = b * 4 + w;
            pool_wave<LU>(user_idx, user_feat, emb_user, ef_user, pop_u, int_u,
                          pooled + 0 * SEC, pooled + 1 * SEC, i, lane);
        } else if (b < 2048) {
            const int i = (b - 1024) * 4 + w;
            pool_wave<LI>(pos_idx, pos_feat, emb_item, ef_item, pop_i, int_i,
                          pooled + 2 * SEC, pooled + 3 * SEC, i, lane);
        } else {
            const int i = (b - 2048) * 4 + w;
            pool_wave<LI>(neg_idx, neg_feat, emb_item, ef_item, pop_i, int_i,
                          pooled + 4 * SEC, pooled + 5 * SEC, i, lane);
        }
        return;
    }

    const int pb = b - 3072;
    if (pb < 704) {
        const float* src; short* dst; int r0, c0, src_ld, dst_ld;
        if (pb < 320) {           // enc_W [2560][128] -> encWT [128][2560]
            int tk = pb % 80, tj = pb / 80;
            src = enc_W; dst = encWT; r0 = tk * 32; c0 = tj * 32; src_ld = 128; dst_ld = 2560;
        } else if (pb < 640) {    // dec_W [128][2560] -> decWT [2560][128]
            int tb = pb - 320; int tc = tb % 80, td = tb / 80;
            src = dec_W; dst = decWT; r0 = td * 32; c0 = tc * 32; src_ld = 2560; dst_ld = 128;
        } else if (pb < 656) {
            int tb = pb - 640; int tk = tb % 4, tj = tb / 4;
            src = fc11_W; dst = fc11WT; r0 = tk * 32; c0 = tj * 32; src_ld = 128; dst_ld = 128;
        } else if (pb < 672) {
            int tb = pb - 656; int tk = tb % 4, tj = tb / 4;
            src = fc12_W; dst = fc12WT; r0 = tk * 32; c0 = tj * 32; src_ld = 128; dst_ld = 128;
        } else if (pb < 688) {
            int tb = pb - 672; int tk = tb % 4, tj = tb / 4;
            src = W_pop; dst = wpopT; r0 = tk * 32; c0 = tj * 32; src_ld = 128; dst_ld = 128;
        } else {
            int tb = pb - 688; int tk = tb % 4, tj = tb / 4;
            src = W_int; dst = wintT; r0 = tk * 32; c0 = tj * 32; src_ld = 128; dst_ld = 128;
        }
        for (int q = 0; q < 4; ++q) {
            int e = t + q * 256;
            int r = e >> 5, c = e & 31;
            tile[r][c] = src[(size_t)(r0 + r) * src_ld + (c0 + c)];
        }
        __syncthreads();
        for (int q = 0; q < 4; ++q) {
            int e = t + q * 256;
            int r = e >> 5, c = e & 31;
            dst[(size_t)(c0 + r) * dst_ld + (r0 + c)] = f2bf(tile[c][r]);
        }
    } else {
        int base = (pb - 704) * 1024 + t * 4;
        float4 v = *(const float4*)(ef_item + base);
        short4 o;
        o.x = f2bf(v.x); o.y = f2bf(v.y); o.z = f2bf(v.z); o.w = f2bf(v.w);
        *(short4*)(ef16 + base) = o;
    }
}

// ---------------------------------------------------------------------------
// K2: MFMA encoder with 8 waves (512 thr), K-parity split across wave groups.
// waves 0-3: even l + mu GEMM + z phase. waves 4-7: odd l + lv GEMM.
// ---------------------------------------------------------------------------
__global__ __launch_bounds__(512) void k2_mfma(
    const int* __restrict__ pos_feat, const int* __restrict__ pos_idx,
    const int* __restrict__ comp_idx,
    const float* __restrict__ emb_item, const float* __restrict__ eps,
    const float* __restrict__ enc_b,
    const float* __restrict__ fc11_b, const float* __restrict__ fc12_b,
    const short* __restrict__ encWT, const short* __restrict__ fc11WT,
    const short* __restrict__ fc12WT, const short* __restrict__ ef16,
    short* __restrict__ zbuf, float* __restrict__ k2part)
{
    __shared__ int   featsL[16 * LI];
    __shared__ int   spi[16], sci[16];
    __shared__ __align__(16) short hlds[16 * 128];
    __shared__ float xbuf[16][128];     // enc partials, then logvar(+bias)
    __shared__ float sdots[4][16][3];
    __shared__ float red[512];

    const int t    = threadIdx.x;
    const int i0   = blockIdx.x * 16;
    const int w    = t >> 6;
    const int lane = t & 63;
    const int g    = lane >> 4;
    const int q    = lane & 15;
    const int wcol = w & 3;
    const int wpar = w >> 2;

    if (t < 16)      spi[t] = pos_idx[i0 + t];
    else if (t < 32) sci[t - 16] = comp_idx[i0 + t - 16];
    if (t < 320) featsL[t] = pos_feat[i0 * LI + t];
    __syncthreads();

    const int j0 = wcol * 32 + q;
    const int j1 = j0 + 16;
    const short* bbase0 = encWT + (size_t)j0 * 2560 + g * 8;
    const short* bbase1 = encWT + (size_t)j1 * 2560 + g * 8;

    f32x4 acc0 = {0.f, 0.f, 0.f, 0.f};
    f32x4 acc1 = {0.f, 0.f, 0.f, 0.f};

    for (int l = wpar; l < LI; l += 2) {
        const int f = featsL[q * LI + l];
        const short* arow = ef16 + (size_t)f * DIM + g * 8;
#pragma unroll
        for (int dt = 0; dt < 4; ++dt) {
            const int koff = l * 128 + dt * 32;
            s16x8 a  = *(const s16x8*)(arow + dt * 32);
            s16x8 b0 = *(const s16x8*)(bbase0 + koff);
            s16x8 b1 = *(const s16x8*)(bbase1 + koff);
            acc0 = __builtin_amdgcn_mfma_f32_16x16x32_bf16(a, b0, acc0, 0, 0, 0);
            acc1 = __builtin_amdgcn_mfma_f32_16x16x32_bf16(a, b1, acc1, 0, 0, 0);
        }
    }

    // combine odd-l partials into even-l waves; bias+relu -> hlds (bf16)
    if (wpar == 1) {
#pragma unroll
        for (int r = 0; r < 4; ++r) {
            int s = g * 4 + r;
            xbuf[s][j0] = acc0[r];
            xbuf[s][j1] = acc1[r];
        }
    }
    __syncthreads();
    if (wpar == 0) {
        float eb0 = enc_b[j0], eb1 = enc_b[j1];
#pragma unroll
        for (int r = 0; r < 4; ++r) {
            int s = g * 4 + r;
            float h0 = acc0[r] + xbuf[s][j0] + eb0; h0 = h0 > 0.f ? h0 : 0.f;
            float h1 = acc1[r] + xbuf[s][j1] + eb1; h1 = h1 > 0.f ? h1 : 0.f;
            int swz = (s & 7) << 3;
            hlds[(s * 128 + j0) ^ swz] = f2bf(h0);
            hlds[(s * 128 + j1) ^ swz] = f2bf(h1);
        }
    }
    __syncthreads();

    // mu (waves 0-3) / logvar (waves 4-7), K=128
    const short* WT  = (wpar == 0) ? fc11WT : fc12WT;
    const short* fb0 = WT + (size_t)j0 * DIM + g * 8;
    const short* fb1 = WT + (size_t)j1 * DIM + g * 8;

    f32x4 r0v = {0.f,0.f,0.f,0.f}, r1v = {0.f,0.f,0.f,0.f};
#pragma unroll
    for (int kt = 0; kt < 4; ++kt) {
        int sidx = (q * 128 + kt * 32 + g * 8) ^ ((q & 7) << 3);
        s16x8 a  = *(const s16x8*)&hlds[sidx];
        s16x8 w0 = *(const s16x8*)(fb0 + kt * 32);
        s16x8 w1 = *(const s16x8*)(fb1 + kt * 32);
        r0v = __builtin_amdgcn_mfma_f32_16x16x32_bf16(a, w0, r0v, 0, 0, 0);
        r1v = __builtin_amdgcn_mfma_f32_16x16x32_bf16(a, w1, r1v, 0, 0, 0);
    }

    if (wpar == 1) {   // store logvar (+bias) for the z-phase
        float b12_0 = fc12_b[j0], b12_1 = fc12_b[j1];
#pragma unroll
        for (int r = 0; r < 4; ++r) {
            int s = g * 4 + r;
            xbuf[s][j0] = r0v[r] + b12_0;
            xbuf[s][j1] = r1v[r] + b12_1;
        }
    }
    __syncthreads();

    float kacc = 0.f;
    if (wpar == 0) {
        float b11_0 = fc11_b[j0], b11_1 = fc11_b[j1];
#pragma unroll
        for (int r = 0; r < 4; ++r) {
            const int s = g * 4 + r;
            const int i = i0 + s;
            float m0 = r0v[r] + b11_0, m1 = r1v[r] + b11_1;
            float v0 = xbuf[s][j0],    v1 = xbuf[s][j1];
            float e0 = eps[(size_t)i * DIM + j0];
            float e1 = eps[(size_t)i * DIM + j1];
            float z0 = e0 * expf(0.5f * v0) + m0;
            float z1 = e1 * expf(0.5f * v1) + m1;
            zbuf[(size_t)i * DIM + j0] = f2bf(z0);
            zbuf[(size_t)i * DIM + j1] = f2bf(z1);
            kacc += (1.f + v0 - m0 * m0 - expf(v0)) + (1.f + v1 - m1 * m1 - expf(v1));

            const size_t pb = (size_t)spi[s] * DIM;
            const size_t cb = (size_t)sci[s] * DIM;
            float pe0 = emb_item[pb + j0], pe1 = emb_item[pb + j1];
            float ce0 = emb_item[cb + j0], ce1 = emb_item[cb + j1];
            float zp = z0 * pe0 + z1 * pe1;
            float zc = z0 * ce0 + z1 * ce1;
            float d0 = z0 - pe0, d1 = z1 - pe1;
            float zq = d0 * d0 + d1 * d1;
            for (int m = 8; m >= 1; m >>= 1) {
                zp += __shfl_xor(zp, m, 64);
                zc += __shfl_xor(zc, m, 64);
                zq += __shfl_xor(zq, m, 64);
            }
            if (q == 0) {
                sdots[w][s][0] = zp;
                sdots[w][s][1] = zc;
                sdots[w][s][2] = zq;
            }
        }
    }

    red[t] = -0.5f * kacc;
    __syncthreads();

    if (t < 16) {
        float zp = 0.f, zc = 0.f, zq = 0.f;
        for (int ww = 0; ww < 4; ++ww) {
            zp += sdots[ww][t][0];
            zc += sdots[ww][t][1];
            zq += sdots[ww][t][2];
        }
        float x = zp - zc;
        float ls = (x >= 0.f) ? -log1pf(expf(-x)) : (x - log1pf(expf(x)));
        red[t] += -ls + zq;
    }
    __syncthreads();
    for (int off = 256; off > 0; off >>= 1) {
        if (t < off) red[t] += red[t + off];
        __syncthreads();
    }
    if (t == 0) k2part[blockIdx.x] = red[0];
}

// ---------------------------------------------------------------------------
// K3: MFMA decoder -> mse partial. 8-way column split: 2048 blocks.
// Each wave: 80 cols (5 frags); all B-frags + x-gathers preloaded for MLP.
// ---------------------------------------------------------------------------
__global__ __launch_bounds__(256) void k3_mfma(
    const int* __restrict__ pos_feat,
    const float* __restrict__ ef_item, const float* __restrict__ dec_b,
    const short* __restrict__ decWT, const short* __restrict__ zbuf,
    float* __restrict__ k3part)
{
    __shared__ int   featsL[16 * LI];
    __shared__ float red[256];

    const int t      = threadIdx.x;
    const int cchunk = blockIdx.x >> 8;
    const int sb     = blockIdx.x & 255;
    const int i0     = sb * 16;
    const int w      = t >> 6;
    const int lane   = t & 63;
    const int g      = lane >> 4;
    const int q      = lane & 15;

    if (t < 256) featsL[t] = pos_feat[i0 * LI + t];
    if (t < 64)  featsL[256 + t] = pos_feat[i0 * LI + 256 + t];
    __syncthreads();

    s16x8 za[4];
#pragma unroll
    for (int kt = 0; kt < 4; ++kt)
        za[kt] = *(const s16x8*)(zbuf + (size_t)(i0 + q) * DIM + kt * 32 + g * 8);

    const int cw = cchunk * 320 + w * 80;

    s16x8 bb[5][4];
    float xs[5][4];
    float bias[5];
#pragma unroll
    for (int fp = 0; fp < 5; ++fp) {
        const int c = cw + fp * 16 + q;
        const short* bp = decWT + (size_t)c * DIM + g * 8;
#pragma unroll
        for (int kt = 0; kt < 4; ++kt)
            bb[fp][kt] = *(const s16x8*)(bp + kt * 32);
        const int l = c >> 7, dcol = c & 127;
#pragma unroll
        for (int r = 0; r < 4; ++r)
            xs[fp][r] = ef_item[(size_t)featsL[(g * 4 + r) * LI + l] * DIM + dcol];
        bias[fp] = dec_b[c];
    }

    float macc = 0.f;
#pragma unroll
    for (int fp = 0; fp < 5; ++fp) {
        f32x4 acc = {0.f, 0.f, 0.f, 0.f};
#pragma unroll
        for (int kt = 0; kt < 4; ++kt)
            acc = __builtin_amdgcn_mfma_f32_16x16x32_bf16(za[kt], bb[fp][kt], acc, 0, 0, 0);
#pragma unroll
        for (int r = 0; r < 4; ++r) {
            float dd = acc[r] + bias[fp] - xs[fp][r];
            macc += dd * dd;
        }
    }

    red[t] = macc;
    __syncthreads();
    for (int off = 128; off > 0; off >>= 1) {
        if (t < off) red[t] += red[t + off];
        __syncthreads();
    }
    if (t == 0) k3part[blockIdx.x] = red[0];
}

// ---------------------------------------------------------------------------
// K1b: triplet losses via MFMA + (block 0) final item_vae_loss reduction.
// ---------------------------------------------------------------------------
__global__ __launch_bounds__(256) void k1b_loss_final(
    const float* __restrict__ pooled, const short* __restrict__ wpopT,
    const short* __restrict__ wintT,
    const float* __restrict__ k2part, const float* __restrict__ k3part,
    float* __restrict__ out_hot, float* __restrict__ out_cold,
    float* __restrict__ out_scalar)
{
    __shared__ float sArr[4][16];
    __shared__ float red[256];
    const int t    = threadIdx.x;
    const int w    = t >> 6;
    const int lane = t & 63;
    const int g    = lane >> 4;
    const int q    = lane & 15;
    const int i0   = blockIdx.x * 16;

    const int h     = w >> 1;
    const int other = (w & 1) + 1;
    const float* pu = pooled + (size_t)(0 * 2 + h) * BATCH * DIM;
    const float* po = pooled + (size_t)(other * 2 + h) * BATCH * DIM;
    const short* wT = h ? wintT : wpopT;

    s16x8 afr[4];
#pragma unroll
    for (int kt = 0; kt < 4; ++kt) {
        const size_t off = (size_t)(i0 + q) * DIM + kt * 32 + g * 8;
        f32x4 ua = *(const f32x4*)(pu + off);
        f32x4 ub = *(const f32x4*)(pu + off + 4);
        f32x4 oa = *(const f32x4*)(po + off);
        f32x4 ob = *(const f32x4*)(po + off + 4);
        s16x8 v;
        v[0] = f2bf(ua[0] - oa[0]); v[1] = f2bf(ua[1] - oa[1]);
        v[2] = f2bf(ua[2] - oa[2]); v[3] = f2bf(ua[3] - oa[3]);
        v[4] = f2bf(ub[0] - ob[0]); v[5] = f2bf(ub[1] - ob[1]);
        v[6] = f2bf(ub[2] - ob[2]); v[7] = f2bf(ub[3] - ob[3]);
        afr[kt] = v;
    }

    float sq0 = 0.f, sq1 = 0.f, sq2 = 0.f, sq3 = 0.f;
    for (int fr = 0; fr < 8; ++fr) {
        const short* bb = wT + (size_t)(fr * 16 + q) * DIM + g * 8;
        f32x4 acc = {0.f, 0.f, 0.f, 0.f};
#pragma unroll
        for (int kt = 0; kt < 4; ++kt) {
            s16x8 bfr = *(const s16x8*)(bb + kt * 32);
            acc = __builtin_amdgcn_mfma_f32_16x16x32_bf16(afr[kt], bfr, acc, 0, 0, 0);
        }
        sq0 += acc[0] * acc[0]; sq1 += acc[1] * acc[1];
        sq2 += acc[2] * acc[2]; sq3 += acc[3] * acc[3];
    }
    for (int m = 8; m >= 1; m >>= 1) {
        sq0 += __shfl_xor(sq0, m, 64);
        sq1 += __shfl_xor(sq1, m, 64);
        sq2 += __shfl_xor(sq2, m, 64);
        sq3 += __shfl_xor(sq3, m, 64);
    }
    if (q == 0) {
        sArr[w][g * 4 + 0] = sq0;
        sArr[w][g * 4 + 1] = sq1;
        sArr[w][g * 4 + 2] = sq2;
        sArr[w][g * 4 + 3] = sq3;
    }
    __syncthreads();
    if (t < 16) {
        float v = sArr[0][t] - sArr[1][t] + 1.0f;
        out_hot[i0 + t] = v > 0.f ? v : 0.f;
    } else if (t < 32) {
        int s = t - 16;
        float v = sArr[2][s] - sArr[3][s] + 1.0f;
        out_cold[i0 + s] = v > 0.f ? v : 0.f;
    }

    if (blockIdx.x == 0) {
        float b3 = 0.f;
        for (int qq = t; qq < 2048; qq += 256) b3 += k3part[qq];
        red[t] = k2part[t] + 0.05f * b3;   // mse / LI  (LI = 20)
        __syncthreads();
        for (int off = 128; off > 0; off >>= 1) {
            if (t < off) red[t] += red[t + off];
            __syncthreads();
        }
        if (t == 0) out_scalar[0] = red[0];
    }
}

// ---------------------------------------------------------------------------
extern "C" void kernel_launch(void* const* d_in, const int* in_sizes, int n_in,
                              void* d_out, int out_size, void* d_ws, size_t ws_size,
                              hipStream_t stream) {
    const int*   user_idx  = (const int*)d_in[0];
    const int*   user_feat = (const int*)d_in[1];
    const int*   pos_idx   = (const int*)d_in[2];
    const int*   pos_feat  = (const int*)d_in[3];
    const int*   neg_idx   = (const int*)d_in[4];
    const int*   neg_feat  = (const int*)d_in[5];
    const int*   comp_idx  = (const int*)d_in[6];
    const float* eps       = (const float*)d_in[7];
    const float* emb_user  = (const float*)d_in[8];
    const float* emb_item  = (const float*)d_in[9];
    const float* ef_user   = (const float*)d_in[10];
    const float* ef_item   = (const float*)d_in[11];
    const float* pop_u     = (const float*)d_in[12];
    const float* int_u     = (const float*)d_in[13];
    const float* pop_i     = (const float*)d_in[14];
    const float* int_i     = (const float*)d_in[15];
    const float* W_pop     = (const float*)d_in[16];
    const float* W_int     = (const float*)d_in[18];
    const float* enc_W     = (const float*)d_in[20];
    const float* enc_b     = (const float*)d_in[21];
    const float* dec_W     = (const float*)d_in[22];
    const float* dec_b     = (const float*)d_in[23];
    const float* fc11_W    = (const float*)d_in[24];
    const float* fc11_b    = (const float*)d_in[25];
    const float* fc12_W    = (const float*)d_in[26];
    const float* fc12_b    = (const float*)d_in[27];

    float* out = (float*)d_out;
    char*  ws  = (char*)d_ws;

    short* zbuf   = (short*)(ws);                  // 1,048,576 B
    short* encWT  = (short*)(ws + 1048576);        //   655,360
    short* decWT  = (short*)(ws + 1703936);        //   655,360
    short* fc11WT = (short*)(ws + 2359296);        //    32,768
    short* fc12WT = (short*)(ws + 2392064);        //    32,768
    short* wpopT  = (short*)(ws + 2424832);        //    32,768
    short* wintT  = (short*)(ws + 2457600);        //    32,768
    short* ef16   = (short*)(ws + 2490368);        // 1,280,000
    float* pooled = (float*)(ws + 3770368);        // 12,582,912
    float* k2part = (float*)(ws + 16353280);       // 1,024
    float* k3part = (float*)(ws + 16354304);       // 8,192

    k01_pool_prep<<<dim3(4401), dim3(256), 0, stream>>>(
        user_idx, user_feat, pos_idx, pos_feat, neg_idx, neg_feat,
        emb_user, emb_item, ef_user, ef_item,
        pop_u, int_u, pop_i, int_i,
        enc_W, dec_W, fc11_W, fc12_W, W_pop, W_int,
        pooled, encWT, decWT, fc11WT, fc12WT, wpopT, wintT, ef16);

    k2_mfma<<<dim3(BATCH / 16), dim3(512), 0, stream>>>(
        pos_feat, pos_idx, comp_idx, emb_item, eps,
        enc_b, fc11_b, fc12_b, encWT, fc11WT, fc12WT, ef16,
        zbuf, k2part);

    k3_mfma<<<dim3(2048), dim3(256), 0, stream>>>(
        pos_feat, ef_item, dec_b, decWT, zbuf, k3part);

    k1b_loss_final<<<dim3(BATCH / 16), dim3(256), 0, stream>>>(
        pooled, wpopT, wintT, k2part, k3part,
        out, out + BATCH, out + 2 * BATCH);
}

// Round 6
// 84.974 us; speedup vs baseline: 8.2576x; 1.1053x over previous
//
#include <hip/hip_runtime.h>
#include <math.h>

#define BATCH 4096
#define DIM 128
#define LU 10
#define LI 20

typedef float  f32x4  __attribute__((ext_vector_type(4)));
typedef short  s16x8  __attribute__((ext_vector_type(8)));

// round-to-nearest-even fp32 -> bf16
__device__ __forceinline__ short f2bf(float x) {
    unsigned u = __float_as_uint(x);
    u += 0x7FFFu + ((u >> 16) & 1u);
    return (short)(u >> 16);
}

// ---------------------------------------------------------------------------
// K_prep: transpose+convert weights to bf16, convert ef_item to bf16.
//   blocks [0,320)     : encWT[128][2560]
//   blocks [320,640)   : decWT[2560][128]
//   blocks [640,656)   : fc11WT[128][128]
//   blocks [656,672)   : fc12WT[128][128]
//   blocks [672,688)   : wpopT[128][128]
//   blocks [688,704)   : wintT[128][128]
//   blocks [704,1329)  : ef16[5000*128]
// ---------------------------------------------------------------------------
__global__ __launch_bounds__(256) void k_prep(
    const float* __restrict__ enc_W, const float* __restrict__ dec_W,
    const float* __restrict__ fc11_W, const float* __restrict__ fc12_W,
    const float* __restrict__ W_pop, const float* __restrict__ W_int,
    const float* __restrict__ ef_item,
    short* __restrict__ encWT, short* __restrict__ decWT,
    short* __restrict__ fc11WT, short* __restrict__ fc12WT,
    short* __restrict__ wpopT, short* __restrict__ wintT,
    short* __restrict__ ef16)
{
    __shared__ float tile[32][33];
    const int b = blockIdx.x;
    const int t = threadIdx.x;

    if (b < 704) {
        const float* src; short* dst; int r0, c0, src_ld, dst_ld;
        if (b < 320) {
            int tk = b % 80, tj = b / 80;
            src = enc_W; dst = encWT; r0 = tk * 32; c0 = tj * 32; src_ld = 128; dst_ld = 2560;
        } else if (b < 640) {
            int tb = b - 320; int tc = tb % 80, td = tb / 80;
            src = dec_W; dst = decWT; r0 = td * 32; c0 = tc * 32; src_ld = 2560; dst_ld = 128;
        } else if (b < 656) {
            int tb = b - 640; int tk = tb % 4, tj = tb / 4;
            src = fc11_W; dst = fc11WT; r0 = tk * 32; c0 = tj * 32; src_ld = 128; dst_ld = 128;
        } else if (b < 672) {
            int tb = b - 656; int tk = tb % 4, tj = tb / 4;
            src = fc12_W; dst = fc12WT; r0 = tk * 32; c0 = tj * 32; src_ld = 128; dst_ld = 128;
        } else if (b < 688) {
            int tb = b - 672; int tk = tb % 4, tj = tb / 4;
            src = W_pop; dst = wpopT; r0 = tk * 32; c0 = tj * 32; src_ld = 128; dst_ld = 128;
        } else {
            int tb = b - 688; int tk = tb % 4, tj = tb / 4;
            src = W_int; dst = wintT; r0 = tk * 32; c0 = tj * 32; src_ld = 128; dst_ld = 128;
        }
        for (int q = 0; q < 4; ++q) {
            int e = t + q * 256;
            int r = e >> 5, c = e & 31;
            tile[r][c] = src[(size_t)(r0 + r) * src_ld + (c0 + c)];
        }
        __syncthreads();
        for (int q = 0; q < 4; ++q) {
            int e = t + q * 256;
            int r = e >> 5, c = e & 31;
            dst[(size_t)(c0 + r) * dst_ld + (r0 + c)] = f2bf(tile[c][r]);
        }
    } else {
        int base = (b - 704) * 1024 + t * 4;
        float4 v = *(const float4*)(ef_item + base);
        short4 o;
        o.x = f2bf(v.x); o.y = f2bf(v.y); o.z = f2bf(v.z); o.w = f2bf(v.w);
        *(short4*)(ef16 + base) = o;
    }
}

// ---------------------------------------------------------------------------
// pool_both<L>: 32-lane half-wave pools one (sample, branch), both vectors.
// Writes swizzled fp32 rows into LDS (plds). swz = (s&7)<<3 (float-index XOR).
// ---------------------------------------------------------------------------
template<int L>
__device__ __forceinline__ void pool_both(
    const int* __restrict__ idxp, const int* __restrict__ featp,
    const float* __restrict__ etab, const float* __restrict__ ftab,
    const float* __restrict__ vpop, const float* __restrict__ vint,
    float* __restrict__ rowH, float* __restrict__ rowC,
    int i, int j32, int swz)
{
    const int d = j32 * 4;
    const float4 vp = *(const float4*)(vpop + d);
    const float4 vi = *(const float4*)(vint + d);
    const int idx = idxp[i];
    const float4 f0 = *(const float4*)(etab + (size_t)idx * DIM + d);

    float sp[L + 1], si[L + 1];
    int fidx[L];
    sp[0] = f0.x * vp.x + f0.y * vp.y + f0.z * vp.z + f0.w * vp.w;
    si[0] = f0.x * vi.x + f0.y * vi.y + f0.z * vi.z + f0.w * vi.w;
    unsigned mbits = 1u;
#pragma unroll
    for (int l = 0; l < L; ++l) {
        int f = featp[(size_t)i * L + l];
        fidx[l] = f;
        mbits |= (f != 0 ? 2u : 0u) << l;
        float4 fv = *(const float4*)(ftab + (size_t)f * DIM + d);
        sp[l + 1] = fv.x * vp.x + fv.y * vp.y + fv.z * vp.z + fv.w * vp.w;
        si[l + 1] = fv.x * vi.x + fv.y * vi.y + fv.z * vi.z + fv.w * vi.w;
    }

#pragma unroll
    for (int l = 0; l <= L; ++l) {
        float a = sp[l], b = si[l];
        a += __shfl_xor(a, 1, 64);  b += __shfl_xor(b, 1, 64);
        a += __shfl_xor(a, 2, 64);  b += __shfl_xor(b, 2, 64);
        a += __shfl_xor(a, 4, 64);  b += __shfl_xor(b, 4, 64);
        a += __shfl_xor(a, 8, 64);  b += __shfl_xor(b, 8, 64);
        a += __shfl_xor(a, 16, 64); b += __shfl_xor(b, 16, 64);
        sp[l] = a; si[l] = b;
    }

    float mh = sp[0], mc = si[0];
#pragma unroll
    for (int l = 1; l <= L; ++l) {
        bool v = (mbits >> l) & 1u;
        mh = v ? fmaxf(mh, sp[l]) : mh;
        mc = v ? fmaxf(mc, si[l]) : mc;
    }
    float sh = 0.f, sc = 0.f;
#pragma unroll
    for (int l = 0; l <= L; ++l) {
        bool v = (mbits >> l) & 1u;
        float eh = v ? __expf(sp[l] - mh) : 0.f;
        float ec = v ? __expf(si[l] - mc) : 0.f;
        sp[l] = eh; si[l] = ec;
        sh += eh; sc += ec;
    }
    const float rh = 1.f / sh, rc = 1.f / sc;

    float hx = sp[0] * f0.x, hy = sp[0] * f0.y, hz = sp[0] * f0.z, hw = sp[0] * f0.w;
    float cx = si[0] * f0.x, cy = si[0] * f0.y, cz = si[0] * f0.z, cw = si[0] * f0.w;
#pragma unroll
    for (int l = 0; l < L; ++l) {
        float4 fv = *(const float4*)(ftab + (size_t)fidx[l] * DIM + d);
        float wh = sp[l + 1], wc = si[l + 1];
        hx += wh * fv.x; hy += wh * fv.y; hz += wh * fv.z; hw += wh * fv.w;
        cx += wc * fv.x; cy += wc * fv.y; cz += wc * fv.z; cw += wc * fv.w;
    }
    const int ci = d ^ swz;
    float4 oH; oH.x = hx * rh; oH.y = hy * rh; oH.z = hz * rh; oH.w = hw * rh;
    float4 oC; oC.x = cx * rc; oC.y = cy * rc; oC.z = cz * rc; oC.w = cw * rc;
    *(float4*)(rowH + ci) = oH;
    *(float4*)(rowC + ci) = oC;
}

// ---------------------------------------------------------------------------
// K_main: 512 blocks x 512 threads.
//   blocks [0,256)   : fused VAE (enc -> mu/lv -> z -> dec + all partials)
//   blocks [256,512) : fused pool (3 branches, LDS) + triplet loss MFMA
// ---------------------------------------------------------------------------
struct PoolS {
    float plds[6][16][128];   // 49152 B (swizzled rows)
    float sArr[4][2][16];     //   512 B
};
struct VaeS {
    int   featsL[320];
    int   spi[16];
    int   sci[16];
    short hlds[2048];         // h1, then z (bf16, swizzled)
    float xbuf[16][128];      // enc partials, then logvar(+bias)
    float sdots[4][16][3];
    float red[512];
};

__global__ __launch_bounds__(512) void k_main(
    const int* __restrict__ user_idx, const int* __restrict__ user_feat,
    const int* __restrict__ pos_idx,  const int* __restrict__ pos_feat,
    const int* __restrict__ neg_idx,  const int* __restrict__ neg_feat,
    const int* __restrict__ comp_idx,
    const float* __restrict__ emb_user, const float* __restrict__ emb_item,
    const float* __restrict__ ef_user,  const float* __restrict__ ef_item,
    const float* __restrict__ pop_u, const float* __restrict__ int_u,
    const float* __restrict__ pop_i, const float* __restrict__ int_i,
    const float* __restrict__ eps,
    const float* __restrict__ enc_b, const float* __restrict__ dec_b,
    const float* __restrict__ fc11_b, const float* __restrict__ fc12_b,
    const short* __restrict__ encWT, const short* __restrict__ decWT,
    const short* __restrict__ fc11WT, const short* __restrict__ fc12WT,
    const short* __restrict__ wpopT, const short* __restrict__ wintT,
    const short* __restrict__ ef16,
    float* __restrict__ out_hot, float* __restrict__ out_cold,
    float* __restrict__ k23part)
{
    __shared__ __align__(16) char smraw[sizeof(PoolS)];
    const int t    = threadIdx.x;
    const int w    = t >> 6;
    const int lane = t & 63;
    const int g    = lane >> 4;
    const int q    = lane & 15;

    if (blockIdx.x >= 256) {
        // ================= POOL + TRIPLET-LOSS BLOCK =================
        PoolS& P = *reinterpret_cast<PoolS*>(smraw);
        const int pb  = blockIdx.x - 256;
        const int i0  = pb * 16;
        const int hw  = t >> 5;          // half-wave = sample
        const int j32 = t & 31;
        const int s   = hw;
        const int i   = i0 + s;
        const int swz = (s & 7) << 3;

        pool_both<LU>(user_idx, user_feat, emb_user, ef_user, pop_u, int_u,
                      &P.plds[0][s][0], &P.plds[1][s][0], i, j32, swz);
        pool_both<LI>(pos_idx, pos_feat, emb_item, ef_item, pop_i, int_i,
                      &P.plds[2][s][0], &P.plds[3][s][0], i, j32, swz);
        pool_both<LI>(neg_idx, neg_feat, emb_item, ef_item, pop_i, int_i,
                      &P.plds[4][s][0], &P.plds[5][s][0], i, j32, swz);
        __syncthreads();

        // loss: wave w -> matrix m = w>>1 (0:hot/pos 1:hot/neg 2:cold/pos
        // 3:cold/neg), half fh = w&1 owns 4 of the 8 col-frags.
        const int m  = w >> 1;
        const int fh = w & 1;
        const int uu = (m < 2) ? 0 : 1;
        const int oo = (m == 0) ? 2 : (m == 1) ? 4 : (m == 2) ? 3 : 5;
        const short* wT = (m < 2) ? wpopT : wintT;

        const float* pu = &P.plds[uu][q][0];
        const float* po = &P.plds[oo][q][0];
        s16x8 afr[4];
#pragma unroll
        for (int kt = 0; kt < 4; ++kt) {
            const int c0 = (kt * 32 + g * 8) ^ ((q & 7) << 3);
            f32x4 ua = *(const f32x4*)(pu + c0);
            f32x4 ub = *(const f32x4*)(pu + c0 + 4);
            f32x4 oa = *(const f32x4*)(po + c0);
            f32x4 ob = *(const f32x4*)(po + c0 + 4);
            s16x8 v;
            v[0] = f2bf(ua[0] - oa[0]); v[1] = f2bf(ua[1] - oa[1]);
            v[2] = f2bf(ua[2] - oa[2]); v[3] = f2bf(ua[3] - oa[3]);
            v[4] = f2bf(ub[0] - ob[0]); v[5] = f2bf(ub[1] - ob[1]);
            v[6] = f2bf(ub[2] - ob[2]); v[7] = f2bf(ub[3] - ob[3]);
            afr[kt] = v;
        }

        float sq0 = 0.f, sq1 = 0.f, sq2 = 0.f, sq3 = 0.f;
#pragma unroll
        for (int ff = 0; ff < 4; ++ff) {
            const int fr = fh * 4 + ff;
            const short* bb = wT + (size_t)(fr * 16 + q) * DIM + g * 8;
            f32x4 acc = {0.f, 0.f, 0.f, 0.f};
#pragma unroll
            for (int kt = 0; kt < 4; ++kt) {
                s16x8 bfr = *(const s16x8*)(bb + kt * 32);
                acc = __builtin_amdgcn_mfma_f32_16x16x32_bf16(afr[kt], bfr, acc, 0, 0, 0);
            }
            sq0 += acc[0] * acc[0]; sq1 += acc[1] * acc[1];
            sq2 += acc[2] * acc[2]; sq3 += acc[3] * acc[3];
        }
        for (int mm = 8; mm >= 1; mm >>= 1) {
            sq0 += __shfl_xor(sq0, mm, 64);
            sq1 += __shfl_xor(sq1, mm, 64);
            sq2 += __shfl_xor(sq2, mm, 64);
            sq3 += __shfl_xor(sq3, mm, 64);
        }
        if (q == 0) {
            P.sArr[m][fh][g * 4 + 0] = sq0;
            P.sArr[m][fh][g * 4 + 1] = sq1;
            P.sArr[m][fh][g * 4 + 2] = sq2;
            P.sArr[m][fh][g * 4 + 3] = sq3;
        }
        __syncthreads();
        if (t < 16) {
            float v = P.sArr[0][0][t] + P.sArr[0][1][t]
                    - P.sArr[1][0][t] - P.sArr[1][1][t] + 1.0f;
            out_hot[i0 + t] = v > 0.f ? v : 0.f;
        } else if (t < 32) {
            int ss = t - 16;
            float v = P.sArr[2][0][ss] + P.sArr[2][1][ss]
                    - P.sArr[3][0][ss] - P.sArr[3][1][ss] + 1.0f;
            out_cold[i0 + ss] = v > 0.f ? v : 0.f;
        }
        return;
    }

    // ====================== FUSED VAE BLOCK ======================
    VaeS& V = *reinterpret_cast<VaeS*>(smraw);
    const int i0   = blockIdx.x * 16;
    const int wcol = w & 3;
    const int wpar = w >> 2;

    if (t < 16)      V.spi[t] = pos_idx[i0 + t];
    else if (t < 32) V.sci[t - 16] = comp_idx[i0 + t - 16];
    if (t < 320) V.featsL[t] = pos_feat[i0 * LI + t];
    __syncthreads();

    const int j0 = wcol * 32 + q;
    const int j1 = j0 + 16;
    const short* bbase0 = encWT + (size_t)j0 * 2560 + g * 8;
    const short* bbase1 = encWT + (size_t)j1 * 2560 + g * 8;

    f32x4 acc0 = {0.f, 0.f, 0.f, 0.f};
    f32x4 acc1 = {0.f, 0.f, 0.f, 0.f};
    for (int l = wpar; l < LI; l += 2) {
        const int f = V.featsL[q * LI + l];
        const short* arow = ef16 + (size_t)f * DIM + g * 8;
#pragma unroll
        for (int dt = 0; dt < 4; ++dt) {
            const int koff = l * 128 + dt * 32;
            s16x8 a  = *(const s16x8*)(arow + dt * 32);
            s16x8 b0 = *(const s16x8*)(bbase0 + koff);
            s16x8 b1 = *(const s16x8*)(bbase1 + koff);
            acc0 = __builtin_amdgcn_mfma_f32_16x16x32_bf16(a, b0, acc0, 0, 0, 0);
            acc1 = __builtin_amdgcn_mfma_f32_16x16x32_bf16(a, b1, acc1, 0, 0, 0);
        }
    }

    if (wpar == 1) {
#pragma unroll
        for (int r = 0; r < 4; ++r) {
            int s = g * 4 + r;
            V.xbuf[s][j0] = acc0[r];
            V.xbuf[s][j1] = acc1[r];
        }
    }
    __syncthreads();
    if (wpar == 0) {
        float eb0 = enc_b[j0], eb1 = enc_b[j1];
#pragma unroll
        for (int r = 0; r < 4; ++r) {
            int s = g * 4 + r;
            float h0 = acc0[r] + V.xbuf[s][j0] + eb0; h0 = h0 > 0.f ? h0 : 0.f;
            float h1 = acc1[r] + V.xbuf[s][j1] + eb1; h1 = h1 > 0.f ? h1 : 0.f;
            int swz = (s & 7) << 3;
            V.hlds[(s * 128 + j0) ^ swz] = f2bf(h0);
            V.hlds[(s * 128 + j1) ^ swz] = f2bf(h1);
        }
    }
    __syncthreads();

    // mu (waves 0-3) / logvar (waves 4-7)
    const short* WT  = (wpar == 0) ? fc11WT : fc12WT;
    const short* fb0 = WT + (size_t)j0 * DIM + g * 8;
    const short* fb1 = WT + (size_t)j1 * DIM + g * 8;
    f32x4 r0v = {0.f,0.f,0.f,0.f}, r1v = {0.f,0.f,0.f,0.f};
#pragma unroll
    for (int kt = 0; kt < 4; ++kt) {
        int sidx = (q * 128 + kt * 32 + g * 8) ^ ((q & 7) << 3);
        s16x8 a  = *(const s16x8*)&V.hlds[sidx];
        s16x8 w0 = *(const s16x8*)(fb0 + kt * 32);
        s16x8 w1 = *(const s16x8*)(fb1 + kt * 32);
        r0v = __builtin_amdgcn_mfma_f32_16x16x32_bf16(a, w0, r0v, 0, 0, 0);
        r1v = __builtin_amdgcn_mfma_f32_16x16x32_bf16(a, w1, r1v, 0, 0, 0);
    }
    if (wpar == 1) {
        float b12_0 = fc12_b[j0], b12_1 = fc12_b[j1];
#pragma unroll
        for (int r = 0; r < 4; ++r) {
            int s = g * 4 + r;
            V.xbuf[s][j0] = r0v[r] + b12_0;
            V.xbuf[s][j1] = r1v[r] + b12_1;
        }
    }
    __syncthreads();

    float kacc = 0.f;
    if (wpar == 0) {
        float b11_0 = fc11_b[j0], b11_1 = fc11_b[j1];
#pragma unroll
        for (int r = 0; r < 4; ++r) {
            const int s = g * 4 + r;
            const int i = i0 + s;
            float m0 = r0v[r] + b11_0, m1 = r1v[r] + b11_1;
            float v0 = V.xbuf[s][j0],  v1 = V.xbuf[s][j1];
            float e0 = eps[(size_t)i * DIM + j0];
            float e1 = eps[(size_t)i * DIM + j1];
            float z0 = e0 * expf(0.5f * v0) + m0;
            float z1 = e1 * expf(0.5f * v1) + m1;
            int swz = (s & 7) << 3;
            V.hlds[(s * 128 + j0) ^ swz] = f2bf(z0);
            V.hlds[(s * 128 + j1) ^ swz] = f2bf(z1);
            kacc += (1.f + v0 - m0 * m0 - expf(v0)) + (1.f + v1 - m1 * m1 - expf(v1));

            const size_t pb2 = (size_t)V.spi[s] * DIM;
            const size_t cb2 = (size_t)V.sci[s] * DIM;
            float pe0 = emb_item[pb2 + j0], pe1 = emb_item[pb2 + j1];
            float ce0 = emb_item[cb2 + j0], ce1 = emb_item[cb2 + j1];
            float zp = z0 * pe0 + z1 * pe1;
            float zc = z0 * ce0 + z1 * ce1;
            float d0 = z0 - pe0, d1 = z1 - pe1;
            float zq = d0 * d0 + d1 * d1;
            for (int mm = 8; mm >= 1; mm >>= 1) {
                zp += __shfl_xor(zp, mm, 64);
                zc += __shfl_xor(zc, mm, 64);
                zq += __shfl_xor(zq, mm, 64);
            }
            if (q == 0) {
                V.sdots[w][s][0] = zp;
                V.sdots[w][s][1] = zc;
                V.sdots[w][s][2] = zq;
            }
        }
    }
    __syncthreads();

    // decoder + mse (all 8 waves): wave w handles cols [w*320, w*320+320)
    s16x8 za[4];
#pragma unroll
    for (int kt = 0; kt < 4; ++kt)
        za[kt] = *(const s16x8*)&V.hlds[(q * 128 + kt * 32 + g * 8) ^ ((q & 7) << 3)];

    const int cw = w * 320;
    float macc = 0.f;
    for (int fp = 0; fp < 10; ++fp) {
        const int c0 = cw + fp * 32 + q;
        const int c1 = c0 + 16;
        const short* bp0 = decWT + (size_t)c0 * DIM + g * 8;
        const short* bp1 = decWT + (size_t)c1 * DIM + g * 8;
        s16x8 b0[4], b1[4];
#pragma unroll
        for (int kt = 0; kt < 4; ++kt) {
            b0[kt] = *(const s16x8*)(bp0 + kt * 32);
            b1[kt] = *(const s16x8*)(bp1 + kt * 32);
        }
        const int l0 = c0 >> 7, d0 = c0 & 127;
        const int l1 = c1 >> 7, d1 = c1 & 127;
        float x0[4], x1[4];
#pragma unroll
        for (int r = 0; r < 4; ++r) {
            x0[r] = ef_item[(size_t)V.featsL[(g * 4 + r) * LI + l0] * DIM + d0];
            x1[r] = ef_item[(size_t)V.featsL[(g * 4 + r) * LI + l1] * DIM + d1];
        }
        const float bias0 = dec_b[c0], bias1 = dec_b[c1];
        f32x4 a0 = {0.f,0.f,0.f,0.f}, a1 = {0.f,0.f,0.f,0.f};
#pragma unroll
        for (int kt = 0; kt < 4; ++kt) {
            a0 = __builtin_amdgcn_mfma_f32_16x16x32_bf16(za[kt], b0[kt], a0, 0, 0, 0);
            a1 = __builtin_amdgcn_mfma_f32_16x16x32_bf16(za[kt], b1[kt], a1, 0, 0, 0);
        }
#pragma unroll
        for (int r = 0; r < 4; ++r) {
            float dd0 = a0[r] + bias0 - x0[r];
            float dd1 = a1[r] + bias1 - x1[r];
            macc += dd0 * dd0 + dd1 * dd1;
        }
    }

    V.red[t] = 0.05f * macc + ((wpar == 0) ? -0.5f * kacc : 0.f);  // mse/LI
    __syncthreads();
    if (t < 16) {
        float zp = 0.f, zc = 0.f, zq = 0.f;
        for (int ww = 0; ww < 4; ++ww) {
            zp += V.sdots[ww][t][0];
            zc += V.sdots[ww][t][1];
            zq += V.sdots[ww][t][2];
        }
        float x = zp - zc;
        float ls = (x >= 0.f) ? -log1pf(expf(-x)) : (x - log1pf(expf(x)));
        V.red[t] += -ls + zq;
    }
    __syncthreads();
    for (int off = 256; off > 0; off >>= 1) {
        if (t < off) V.red[t] += V.red[t + off];
        __syncthreads();
    }
    if (t == 0) k23part[blockIdx.x] = V.red[0];
}

// ---------------------------------------------------------------------------
// K_final: sum 256 vae partials -> item_vae_loss scalar.
// ---------------------------------------------------------------------------
__global__ __launch_bounds__(256) void k_final(
    const float* __restrict__ k23part, float* __restrict__ out_scalar)
{
    __shared__ float red[256];
    const int t = threadIdx.x;
    red[t] = k23part[t];
    __syncthreads();
    for (int off = 128; off > 0; off >>= 1) {
        if (t < off) red[t] += red[t + off];
        __syncthreads();
    }
    if (t == 0) out_scalar[0] = red[0];
}

// ---------------------------------------------------------------------------
extern "C" void kernel_launch(void* const* d_in, const int* in_sizes, int n_in,
                              void* d_out, int out_size, void* d_ws, size_t ws_size,
                              hipStream_t stream) {
    const int*   user_idx  = (const int*)d_in[0];
    const int*   user_feat = (const int*)d_in[1];
    const int*   pos_idx   = (const int*)d_in[2];
    const int*   pos_feat  = (const int*)d_in[3];
    const int*   neg_idx   = (const int*)d_in[4];
    const int*   neg_feat  = (const int*)d_in[5];
    const int*   comp_idx  = (const int*)d_in[6];
    const float* eps       = (const float*)d_in[7];
    const float* emb_user  = (const float*)d_in[8];
    const float* emb_item  = (const float*)d_in[9];
    const float* ef_user   = (const float*)d_in[10];
    const float* ef_item   = (const float*)d_in[11];
    const float* pop_u     = (const float*)d_in[12];
    const float* int_u     = (const float*)d_in[13];
    const float* pop_i     = (const float*)d_in[14];
    const float* int_i     = (const float*)d_in[15];
    const float* W_pop     = (const float*)d_in[16];
    const float* W_int     = (const float*)d_in[18];
    const float* enc_W     = (const float*)d_in[20];
    const float* enc_b     = (const float*)d_in[21];
    const float* dec_W     = (const float*)d_in[22];
    const float* dec_b     = (const float*)d_in[23];
    const float* fc11_W    = (const float*)d_in[24];
    const float* fc11_b    = (const float*)d_in[25];
    const float* fc12_W    = (const float*)d_in[26];
    const float* fc12_b    = (const float*)d_in[27];

    float* out = (float*)d_out;
    char*  ws  = (char*)d_ws;

    short* encWT   = (short*)(ws);                    //   655,360 B
    short* decWT   = (short*)(ws + 655360);           //   655,360
    short* fc11WT  = (short*)(ws + 1310720);          //    32,768
    short* fc12WT  = (short*)(ws + 1343488);          //    32,768
    short* wpopT   = (short*)(ws + 1376256);          //    32,768
    short* wintT   = (short*)(ws + 1409024);          //    32,768
    short* ef16    = (short*)(ws + 1441792);          // 1,280,000
    float* k23part = (float*)(ws + 2721792);          //     1,024

    k_prep<<<dim3(1329), dim3(256), 0, stream>>>(
        enc_W, dec_W, fc11_W, fc12_W, W_pop, W_int, ef_item,
        encWT, decWT, fc11WT, fc12WT, wpopT, wintT, ef16);

    k_main<<<dim3(512), dim3(512), 0, stream>>>(
        user_idx, user_feat, pos_idx, pos_feat, neg_idx, neg_feat, comp_idx,
        emb_user, emb_item, ef_user, ef_item,
        pop_u, int_u, pop_i, int_i,
        eps, enc_b, dec_b, fc11_b, fc12_b,
        encWT, decWT, fc11WT, fc12WT, wpopT, wintT, ef16,
        out, out + BATCH, k23part);

    k_final<<<dim3(1), dim3(256), 0, stream>>>(k23part, out + 2 * BATCH);
}